// Round 4
// baseline (990.884 us; speedup 1.0000x reference)
//
#include <hip/hip_runtime.h>

#define D 128
#define EPS 1e-5f

typedef unsigned int uint;
typedef __attribute__((ext_vector_type(4))) float f32x4;
typedef __attribute__((ext_vector_type(8))) short s16x8;

// ---- bf16 pack/unpack helpers (RTNE) ---------------------------------------
__device__ __forceinline__ uint pack_bf16(float a, float b)
{
    uint ua = __float_as_uint(a);
    uint ub = __float_as_uint(b);
    ua += 0x7FFFu + ((ua >> 16) & 1u);
    ub += 0x7FFFu + ((ub >> 16) & 1u);
    return (ua >> 16) | (ub & 0xFFFF0000u);
}
__device__ __forceinline__ float bf_lo(uint v) { return __uint_as_float(v << 16); }
__device__ __forceinline__ float bf_hi(uint v) { return __uint_as_float(v & 0xFFFF0000u); }

struct MP {
    const float *x, *w1l, *b1l, *w1r, *w2l, *b2l, *w2r, *gamma, *beta;
    const int *src, *dst;
    float *outf;
    uint *xb, *aggb, *hb, *hbn, *wb1, *wb2;
    int *rowptr, *cursor, *col, *bsum, *bar;
    float *pstats, *stats, *scsh;
    int n, e;
};

// ---- two-level grid barrier (monotone counters, host-zeroed per launch) ----
// bar[g*32] : level-1 counter for 16-block group g (128B apart)
// bar[4096] : level-2 generation counter (one increment per group per phase)
__device__ __forceinline__ void grid_barrier(int* bar, int G, int phase)
{
    __syncthreads();
    if (threadIdx.x == 0) {
        __threadfence();                       // release our phase's writes (wb L2)
        int g = blockIdx.x >> 4;
        int ngroups = (G + 15) >> 4;
        int members = min(16, G - (g << 4));
        int a = __hip_atomic_fetch_add(&bar[g * 32], 1, __ATOMIC_ACQ_REL,
                                       __HIP_MEMORY_SCOPE_AGENT);
        if (a + 1 == phase * members)
            __hip_atomic_fetch_add(&bar[4096], 1, __ATOMIC_ACQ_REL,
                                   __HIP_MEMORY_SCOPE_AGENT);
        while (__hip_atomic_load(&bar[4096], __ATOMIC_ACQUIRE,
                                 __HIP_MEMORY_SCOPE_AGENT) < phase * ngroups)
            __builtin_amdgcn_s_sleep(2);
        __threadfence();                       // acquire: invalidate stale lines
    }
    __syncthreads();
}

// ---- aggregation phase: wave per node, 16-slot batches (v0 structure) ------
__device__ __forceinline__ void agg_phase(const int* __restrict__ rowptr,
                                          const int* __restrict__ col,
                                          const uint* __restrict__ featb,
                                          uint* __restrict__ aggb, int n, int G)
{
    int tid = threadIdx.x;
    int wid = tid >> 6, lane = tid & 63;
    int sub = lane >> 4, l16 = lane & 15;
    const uint4* fb = (const uint4*)featb;
    uint4* out4 = (uint4*)aggb;
    int nlb = (n + 3) >> 2;
    for (int lb = blockIdx.x; lb < nlb; lb += G) {
        int node = lb * 4 + wid;
        if (node >= n) continue;
        int r0 = rowptr[node], r1 = rowptr[node + 1];
        if (r0 == r1) {
            if (lane < 16) out4[(size_t)node * 16 + l16] = make_uint4(0, 0, 0, 0);
            continue;
        }
        float acc[8] = {0.f, 0.f, 0.f, 0.f, 0.f, 0.f, 0.f, 0.f};
        int last = r1 - 1;
        for (int i = r0; i < r1; i += 16) {
            uint4 v[4];
#pragma unroll
            for (int r = 0; r < 4; r++) {
                int idx = i + r * 4 + sub;
                int cl = col[min(idx, last)];
                int c = (idx < r1) ? cl : n;       // n = zero row
                v[r] = fb[(size_t)c * 16 + l16];
            }
#pragma unroll
            for (int r = 0; r < 4; r++) {
                uint4 u = v[r];
                acc[0] += bf_lo(u.x); acc[1] += bf_hi(u.x);
                acc[2] += bf_lo(u.y); acc[3] += bf_hi(u.y);
                acc[4] += bf_lo(u.z); acc[5] += bf_hi(u.z);
                acc[6] += bf_lo(u.w); acc[7] += bf_hi(u.w);
            }
        }
#pragma unroll
        for (int j = 0; j < 8; j++) {
            acc[j] += __shfl_down(acc[j], 32);
            acc[j] += __shfl_down(acc[j], 16);
        }
        if (lane < 16) {
            float inv = 1.0f / (float)(r1 - r0);
            uint4 o;
            o.x = pack_bf16(acc[0] * inv, acc[1] * inv);
            o.y = pack_bf16(acc[2] * inv, acc[3] * inv);
            o.z = pack_bf16(acc[4] * inv, acc[5] * inv);
            o.w = pack_bf16(acc[6] * inv, acc[7] * inv);
            out4[(size_t)node * 16 + l16] = o;
        }
    }
}

// ---- conv phase: LDS-free. FUSE1 packs hb via shfl_xor column pairing and
// accumulates BN column stats in registers (shfl quad-reduce at phase end). ---
template<bool FUSE1>
__device__ __forceinline__ void conv_phase(const uint* __restrict__ p1b,
                                           const uint* __restrict__ p2b,
                                           const uint* __restrict__ wb,
                                           const float* __restrict__ bias,
                                           float* __restrict__ outf,
                                           uint* __restrict__ outb,
                                           float* __restrict__ pstats,
                                           int n, int G)
{
    int tid = threadIdx.x;
    int w = tid >> 6, lane = tid & 63;
    int quad = lane >> 4, l15 = lane & 15;
    const uint4* p1 = (const uint4*)p1b;
    const uint4* p2 = (const uint4*)p2b;
    const uint4* wv = (const uint4*)wb;

    uint4 B[8][2];
    int nt0 = w * 2;
#pragma unroll
    for (int ks = 0; ks < 8; ks++) {
#pragma unroll
        for (int t = 0; t < 2; t++)
            B[ks][t] = wv[(ks * 8 + nt0 + t) * 64 + lane];
    }
    float bv0 = bias[nt0 * 16 + l15];
    float bv1 = bias[nt0 * 16 + 16 + l15];

    float s0 = 0.f, ss0 = 0.f, s1 = 0.f, ss1 = 0.f;
    int ncb = (n + 63) >> 6;
    for (int cb = blockIdx.x; cb < ncb; cb += G) {
        int nb = cb * 64;
        for (int rt = 0; rt < 4; rt++) {
            int node = nb + rt * 16 + l15;
            int nc = min(node, n - 1);
            uint4 A[8];
#pragma unroll
            for (int ks = 0; ks < 4; ks++) A[ks] = p1[(size_t)nc * 16 + ks * 4 + quad];
#pragma unroll
            for (int ks = 0; ks < 4; ks++) A[ks + 4] = p2[(size_t)nc * 16 + ks * 4 + quad];

            f32x4 acc0 = {bv0, bv0, bv0, bv0};
            f32x4 acc1 = {bv1, bv1, bv1, bv1};
#pragma unroll
            for (int ks = 0; ks < 8; ks++) {
                s16x8 a = *(s16x8*)&A[ks];
                acc0 = __builtin_amdgcn_mfma_f32_16x16x32_bf16(a, *(s16x8*)&B[ks][0], acc0, 0, 0, 0);
                acc1 = __builtin_amdgcn_mfma_f32_16x16x32_bf16(a, *(s16x8*)&B[ks][1], acc1, 0, 0, 0);
            }
            // C/D: col = lane&15, row = quad*4 + reg
            int row0 = nb + rt * 16 + quad * 4;
            int colbase = nt0 * 16 + l15;
#pragma unroll
            for (int reg = 0; reg < 4; reg++) {
                int row = row0 + reg;
                bool ok = row < n;
                if (FUSE1) {
                    float v0 = ok ? acc0[reg] : 0.f;
                    float v1 = ok ? acc1[reg] : 0.f;
                    s0 += v0; ss0 += v0 * v0;
                    s1 += v1; ss1 += v1 * v1;
                    float w0 = __shfl_xor(v0, 1);
                    float w1 = __shfl_xor(v1, 1);
                    if (!(l15 & 1) && ok) {
                        uint* orow = outb + (size_t)row * 64 + nt0 * 8 + (l15 >> 1);
                        orow[0] = pack_bf16(v0, w0);
                        orow[8] = pack_bf16(v1, w1);
                    }
                } else {
                    if (ok) {
                        outf[(size_t)row * D + colbase] = acc0[reg];
                        outf[(size_t)row * D + colbase + 16] = acc1[reg];
                    }
                }
            }
        }
    }
    if (FUSE1) {
        // reduce column partials across quads: lanes l15, l15+16, l15+32, l15+48
        s0 += __shfl_down(s0, 32);  s0 += __shfl_down(s0, 16);
        ss0 += __shfl_down(ss0, 32); ss0 += __shfl_down(ss0, 16);
        s1 += __shfl_down(s1, 32);  s1 += __shfl_down(s1, 16);
        ss1 += __shfl_down(ss1, 32); ss1 += __shfl_down(ss1, 16);
        if (lane < 16) {
            float* pb = pstats + (size_t)blockIdx.x * 256;
            int c0 = nt0 * 16 + l15;
            pb[c0] = s0;       pb[128 + c0] = ss0;
            pb[c0 + 16] = s1;  pb[128 + c0 + 16] = ss1;
        }
    }
}

// ---- the mega kernel: entire pipeline, 12 grid barriers --------------------
__global__ __launch_bounds__(256, 4) void mega_kernel(MP p)
{
    __shared__ int ism[256];
    __shared__ float scs[256];
    int G = gridDim.x, bid = blockIdx.x, tid = threadIdx.x;
    int n = p.n, e = p.e;
    int ph = 0;

    // P0: prep xb (bf16 + zero row) & weight frags; zero deg(cursor) & stats
    {
        int ncvt = n * 32;
        int total0 = ncvt + 8192 + 32;
        for (int idx = bid * 256 + tid; idx < total0; idx += G * 256) {
            if (idx < ncvt) {
                float4 v = ((const float4*)p.x)[idx];
                uint2 o;
                o.x = pack_bf16(v.x, v.y);
                o.y = pack_bf16(v.z, v.w);
                ((uint2*)p.xb)[idx] = o;
            } else if (idx < ncvt + 8192) {
                int r = idx - ncvt;
                int layer = r >> 12;
                int rem = r & 4095;
                int lane = rem & 63;
                int knt = rem >> 6;
                int kstep = knt >> 3, nt = knt & 7;
                int nn = nt * 16 + (lane & 15);
                int kbase = kstep * 32 + (lane >> 4) * 8;
                const float* wl = layer ? p.w2l : p.w1l;
                const float* wr = layer ? p.w2r : p.w1r;
                uint* wbp = layer ? p.wb2 : p.wb1;
                float v[8];
#pragma unroll
                for (int j = 0; j < 8; j++) {
                    int k = kbase + j;
                    v[j] = (k < D) ? wl[nn * D + k] : wr[nn * D + (k - D)];
                }
                uint4 o;
                o.x = pack_bf16(v[0], v[1]);
                o.y = pack_bf16(v[2], v[3]);
                o.z = pack_bf16(v[4], v[5]);
                o.w = pack_bf16(v[6], v[7]);
                ((uint4*)wbp)[(kstep * 8 + nt) * 64 + lane] = o;
            } else {
                ((uint2*)p.xb)[ncvt + (idx - ncvt - 8192)] = make_uint2(0, 0);
            }
        }
        for (int i = bid * 256 + tid; i < n; i += G * 256) p.cursor[i] = 0;
        if (bid == 0) p.stats[tid] = 0.f;
    }
    grid_barrier(p.bar, G, ++ph);

    // P1: degree histogram (random scatter atomics, ~16/address)
    for (int i = bid * 256 + tid; i < e; i += G * 256)
        atomicAdd(&p.cursor[p.dst[i]], 1);
    grid_barrier(p.bar, G, ++ph);

    // P2: block-local exclusive scan of degrees (256 per scan-block)
    {
        int nsb = (n + 255) >> 8;
        for (int sb = bid; sb < nsb; sb += G) {
            int idx = sb * 256 + tid;
            int v = (idx < n) ? p.cursor[idx] : 0;
            ism[tid] = v;
            __syncthreads();
            for (int off = 1; off < 256; off <<= 1) {
                int u = (tid >= off) ? ism[tid - off] : 0;
                __syncthreads();
                ism[tid] += u;
                __syncthreads();
            }
            if (idx < n) p.rowptr[idx] = ism[tid] - v;
            if (tid == 255) p.bsum[sb] = ism[255];
            __syncthreads();
        }
    }
    grid_barrier(p.bar, G, ++ph);

    // P3: scan of block sums (block 0; nsb <= 256)
    if (bid == 0) {
        int nsb = (n + 255) >> 8;
        int v = (tid < nsb) ? p.bsum[tid] : 0;
        ism[tid] = v;
        __syncthreads();
        for (int off = 1; off < 256; off <<= 1) {
            int u = (tid >= off) ? ism[tid - off] : 0;
            __syncthreads();
            ism[tid] += u;
            __syncthreads();
        }
        if (tid < nsb) p.bsum[tid] = ism[tid] - v;
        if (tid == 0) p.rowptr[n] = e;
    }
    grid_barrier(p.bar, G, ++ph);

    // P4: add scan-block base; init scatter cursors
    for (int i = bid * 256 + tid; i < n; i += G * 256) {
        int r = p.rowptr[i] + p.bsum[i >> 8];
        p.rowptr[i] = r;
        p.cursor[i] = r;
    }
    grid_barrier(p.bar, G, ++ph);

    // P5: edge scatter into CSR col
    for (int i = bid * 256 + tid; i < e; i += G * 256) {
        int pp = atomicAdd(&p.cursor[p.dst[i]], 1);
        p.col[pp] = p.src[i];
    }
    grid_barrier(p.bar, G, ++ph);

    // P6: agg layer 1
    agg_phase(p.rowptr, p.col, p.xb, p.aggb, n, G);
    grid_barrier(p.bar, G, ++ph);

    // P7: conv layer 1 (+hb pack, +BN partials)
    conv_phase<true>(p.aggb, p.xb, p.wb1, p.b1l, nullptr, p.hb, p.pstats, n, G);
    grid_barrier(p.bar, G, ++ph);

    // P8: reduce BN partials (32 blocks, 32 atomics/address)
    if (bid < 32) {
        int nparts = G;
        int chunk = (nparts + 31) >> 5;
        int q0 = bid * chunk, q1 = min(q0 + chunk, nparts);
        float s = 0.f;
        for (int q = q0; q < q1; q++) s += p.pstats[(size_t)q * 256 + tid];
        unsafeAtomicAdd(&p.stats[tid], s);
    }
    grid_barrier(p.bar, G, ++ph);

    // P9: finalize BN scale/shift
    if (bid == 0 && tid < 128) {
        float n_inv = 1.0f / (float)n;
        float mean = p.stats[tid] * n_inv;
        float var = fmaxf(p.stats[128 + tid] * n_inv - mean * mean, 0.f);
        float sc = p.gamma[tid] * rsqrtf(var + EPS);
        p.scsh[tid] = sc;
        p.scsh[128 + tid] = p.beta[tid] - mean * sc;
    }
    grid_barrier(p.bar, G, ++ph);

    // P10: bnapply (relu(hb*sc+sh) -> hbn bf16, + zero row)
    {
        scs[tid] = p.scsh[tid];
        __syncthreads();
        int total2 = n * 32;
        for (int idx = bid * 256 + tid; idx < total2; idx += G * 256) {
            int j4 = (idx & 31) * 4;
            uint2 u = ((const uint2*)p.hb)[idx];
            float e0 = fmaxf(bf_lo(u.x) * scs[j4 + 0] + scs[128 + j4 + 0], 0.f);
            float e1 = fmaxf(bf_hi(u.x) * scs[j4 + 1] + scs[128 + j4 + 1], 0.f);
            float e2 = fmaxf(bf_lo(u.y) * scs[j4 + 2] + scs[128 + j4 + 2], 0.f);
            float e3 = fmaxf(bf_hi(u.y) * scs[j4 + 3] + scs[128 + j4 + 3], 0.f);
            uint2 o;
            o.x = pack_bf16(e0, e1);
            o.y = pack_bf16(e2, e3);
            ((uint2*)p.hbn)[idx] = o;
        }
        if (bid == 0 && tid < 32)
            ((uint2*)p.hbn)[total2 + tid] = make_uint2(0, 0);
    }
    grid_barrier(p.bar, G, ++ph);

    // P11: agg layer 2
    agg_phase(p.rowptr, p.col, p.hbn, p.aggb, n, G);
    grid_barrier(p.bar, G, ++ph);

    // P12: conv layer 2 -> fp32 output
    conv_phase<false>(p.aggb, p.hbn, p.wb2, p.b2l, p.outf, nullptr, nullptr, n, G);
}

extern "C" void kernel_launch(void* const* d_in, const int* in_sizes, int n_in,
                              void* d_out, int out_size, void* d_ws, size_t ws_size,
                              hipStream_t stream)
{
    const float* x     = (const float*)d_in[0];
    const int*   ei    = (const int*)d_in[1];
    const float* w1_l  = (const float*)d_in[2];
    const float* b1_l  = (const float*)d_in[3];
    const float* w1_r  = (const float*)d_in[4];
    const float* w2_l  = (const float*)d_in[5];
    const float* b2_l  = (const float*)d_in[6];
    const float* w2_r  = (const float*)d_in[7];
    const float* gamma = (const float*)d_in[8];
    const float* beta  = (const float*)d_in[9];

    int N = in_sizes[0] / D;
    int E = in_sizes[1] / 2;

    // workspace layout
    uint*  aggb   = (uint*)d_ws;
    uint*  xb     = aggb + (size_t)N * 64;
    uint*  hb     = xb + (size_t)(N + 1) * 64;
    uint*  hbn    = hb + (size_t)N * 64;
    uint*  wb1    = hbn + (size_t)(N + 1) * 64;
    uint*  wb2    = wb1 + 16384;
    float* pstats = (float*)(wb2 + 16384);          // up to 2048 blocks * 256
    float* stats  = pstats + (size_t)2048 * 256;
    float* scsh   = stats + 256;
    int*   rowptr = (int*)(scsh + 256);
    int*   cursor = rowptr + (N + 1);
    int*   col    = cursor + N;
    int*   bsum   = col + E;
    int*   bar    = bsum + 256;                     // 4097 ints used

    // grid size: blocks/CU from occupancy query (co-residency for the barrier)
    static int g_blocks = 0;
    if (g_blocks == 0) {
        int mb = 0;
        if (hipOccupancyMaxActiveBlocksPerMultiprocessor(&mb, mega_kernel, 256, 0)
                != hipSuccess || mb < 1)
            mb = 1;
        if (mb > 8) mb = 8;
        int cu = 256;
        int dev = 0;
        hipDeviceProp_t prop;
        if (hipGetDevice(&dev) == hipSuccess &&
            hipGetDeviceProperties(&prop, dev) == hipSuccess &&
            prop.multiProcessorCount > 0)
            cu = prop.multiProcessorCount;
        g_blocks = mb * cu;
        if (g_blocks > 2048) g_blocks = 2048;
        if (g_blocks < 64) g_blocks = 64;
    }

    hipMemsetAsync(bar, 0, 4104 * sizeof(int), stream);

    MP p;
    p.x = x; p.w1l = w1_l; p.b1l = b1_l; p.w1r = w1_r;
    p.w2l = w2_l; p.b2l = b2_l; p.w2r = w2_r;
    p.gamma = gamma; p.beta = beta;
    p.src = ei; p.dst = ei + E;
    p.outf = (float*)d_out;
    p.xb = xb; p.aggb = aggb; p.hb = hb; p.hbn = hbn; p.wb1 = wb1; p.wb2 = wb2;
    p.rowptr = rowptr; p.cursor = cursor; p.col = col; p.bsum = bsum; p.bar = bar;
    p.pstats = pstats; p.stats = stats; p.scsh = scsh;
    p.n = N; p.e = E;

    mega_kernel<<<g_blocks, 256, 0, stream>>>(p);
}

// Round 5
// 671.902 us; speedup vs baseline: 1.4747x; 1.4747x over previous
//
#include <hip/hip_runtime.h>

#define D 128
#define EPS 1e-5f

typedef unsigned int uint;
typedef __attribute__((ext_vector_type(4))) float f32x4;
typedef __attribute__((ext_vector_type(8))) short s16x8;

// ---- bf16 pack/unpack helpers (RTNE) ---------------------------------------
__device__ __forceinline__ uint pack_bf16(float a, float b)
{
    uint ua = __float_as_uint(a);
    uint ub = __float_as_uint(b);
    ua += 0x7FFFu + ((ua >> 16) & 1u);
    ub += 0x7FFFu + ((ub >> 16) & 1u);
    return (ua >> 16) | (ub & 0xFFFF0000u);
}
__device__ __forceinline__ float bf_lo(uint v) { return __uint_as_float(v << 16); }
__device__ __forceinline__ float bf_hi(uint v) { return __uint_as_float(v & 0xFFFF0000u); }

struct MP {
    const float *x, *w1l, *b1l, *w1r, *w2l, *b2l, *w2r, *gamma, *beta;
    const int *src, *dst;
    float *outf;
    uint *xb, *aggb, *hb, *hbn, *wb1, *wb2;
    int *rowptr, *cursor, *col, *bsum, *bar, *scanctr, *redctr;
    float *pstats, *stats, *scsh;
    int n, e;
};

// ---- two-level grid barrier v2 ---------------------------------------------
// bar[g*32] : level-1 counter for 16-block group g (128B apart)
// bar[4096] : level-2 generation counter (one increment per group per phase)
// KEY FIX vs v1: poll with RELAXED atomic load (no per-poll cache invalidate;
// v1's ACQUIRE-per-poll buffer_inv storms poisoned co-resident blocks' L1 and
// made each barrier ~125us). Single acquire fence after exit.
__device__ __forceinline__ void grid_barrier(int* bar, int G, int phase)
{
    __syncthreads();
    if (threadIdx.x == 0) {
        __threadfence();                       // release this phase's writes
        int g = blockIdx.x >> 4;
        int ngroups = (G + 15) >> 4;
        int members = min(16, G - (g << 4));
        int a = __hip_atomic_fetch_add(&bar[g * 32], 1, __ATOMIC_ACQ_REL,
                                       __HIP_MEMORY_SCOPE_AGENT);
        if (a + 1 == phase * members)
            __hip_atomic_fetch_add(&bar[4096], 1, __ATOMIC_ACQ_REL,
                                   __HIP_MEMORY_SCOPE_AGENT);
        int target = phase * ngroups;
        while (__hip_atomic_load(&bar[4096], __ATOMIC_RELAXED,
                                 __HIP_MEMORY_SCOPE_AGENT) < target)
            __builtin_amdgcn_s_sleep(16);
        __threadfence();                       // acquire: invalidate stale lines once
    }
    __syncthreads();
}

// ---- intra-phase last-block-done (proven R2/R3 pattern) --------------------
__device__ __forceinline__ bool last_done(int* ctr, int total, int* flag)
{
    __syncthreads();
    if (threadIdx.x == 0) {
        __threadfence();
        int old = __hip_atomic_fetch_add(ctr, 1, __ATOMIC_ACQ_REL,
                                         __HIP_MEMORY_SCOPE_AGENT);
        *flag = (old == total - 1) ? 1 : 0;
        if (*flag) __threadfence();
    }
    __syncthreads();
    return *flag != 0;
}

// ---- aggregation phase: wave per node, 16-slot batches (v0 structure) ------
__device__ __forceinline__ void agg_phase(const int* __restrict__ rowptr,
                                          const int* __restrict__ col,
                                          const uint* __restrict__ featb,
                                          uint* __restrict__ aggb, int n, int G)
{
    int tid = threadIdx.x;
    int wid = tid >> 6, lane = tid & 63;
    int sub = lane >> 4, l16 = lane & 15;
    const uint4* fb = (const uint4*)featb;
    uint4* out4 = (uint4*)aggb;
    int nlb = (n + 3) >> 2;
    for (int lb = blockIdx.x; lb < nlb; lb += G) {
        int node = lb * 4 + wid;
        if (node >= n) continue;
        int r0 = rowptr[node], r1 = rowptr[node + 1];
        if (r0 == r1) {
            if (lane < 16) out4[(size_t)node * 16 + l16] = make_uint4(0, 0, 0, 0);
            continue;
        }
        float acc[8] = {0.f, 0.f, 0.f, 0.f, 0.f, 0.f, 0.f, 0.f};
        int last = r1 - 1;
        for (int i = r0; i < r1; i += 16) {
            uint4 v[4];
#pragma unroll
            for (int r = 0; r < 4; r++) {
                int idx = i + r * 4 + sub;
                int cl = col[min(idx, last)];
                int c = (idx < r1) ? cl : n;       // n = zero row
                v[r] = fb[(size_t)c * 16 + l16];
            }
#pragma unroll
            for (int r = 0; r < 4; r++) {
                uint4 u = v[r];
                acc[0] += bf_lo(u.x); acc[1] += bf_hi(u.x);
                acc[2] += bf_lo(u.y); acc[3] += bf_hi(u.y);
                acc[4] += bf_lo(u.z); acc[5] += bf_hi(u.z);
                acc[6] += bf_lo(u.w); acc[7] += bf_hi(u.w);
            }
        }
#pragma unroll
        for (int j = 0; j < 8; j++) {
            acc[j] += __shfl_down(acc[j], 32);
            acc[j] += __shfl_down(acc[j], 16);
        }
        if (lane < 16) {
            float inv = 1.0f / (float)(r1 - r0);
            uint4 o;
            o.x = pack_bf16(acc[0] * inv, acc[1] * inv);
            o.y = pack_bf16(acc[2] * inv, acc[3] * inv);
            o.z = pack_bf16(acc[4] * inv, acc[5] * inv);
            o.w = pack_bf16(acc[6] * inv, acc[7] * inv);
            out4[(size_t)node * 16 + l16] = o;
        }
    }
}

// ---- conv phase: LDS-free. FUSE1 packs hb via shfl_xor column pairing and
// accumulates BN column stats in registers (shfl quad-reduce at phase end). ---
template<bool FUSE1>
__device__ __forceinline__ void conv_phase(const uint* __restrict__ p1b,
                                           const uint* __restrict__ p2b,
                                           const uint* __restrict__ wb,
                                           const float* __restrict__ bias,
                                           float* __restrict__ outf,
                                           uint* __restrict__ outb,
                                           float* __restrict__ pstats,
                                           int n, int G)
{
    int tid = threadIdx.x;
    int w = tid >> 6, lane = tid & 63;
    int quad = lane >> 4, l15 = lane & 15;
    const uint4* p1 = (const uint4*)p1b;
    const uint4* p2 = (const uint4*)p2b;
    const uint4* wv = (const uint4*)wb;

    uint4 B[8][2];
    int nt0 = w * 2;
#pragma unroll
    for (int ks = 0; ks < 8; ks++) {
#pragma unroll
        for (int t = 0; t < 2; t++)
            B[ks][t] = wv[(ks * 8 + nt0 + t) * 64 + lane];
    }
    float bv0 = bias[nt0 * 16 + l15];
    float bv1 = bias[nt0 * 16 + 16 + l15];

    float s0 = 0.f, ss0 = 0.f, s1 = 0.f, ss1 = 0.f;
    int ncb = (n + 63) >> 6;
    for (int cb = blockIdx.x; cb < ncb; cb += G) {
        int nb = cb * 64;
        for (int rt = 0; rt < 4; rt++) {
            int node = nb + rt * 16 + l15;
            int nc = min(node, n - 1);
            uint4 A[8];
#pragma unroll
            for (int ks = 0; ks < 4; ks++) A[ks] = p1[(size_t)nc * 16 + ks * 4 + quad];
#pragma unroll
            for (int ks = 0; ks < 4; ks++) A[ks + 4] = p2[(size_t)nc * 16 + ks * 4 + quad];

            f32x4 acc0 = {bv0, bv0, bv0, bv0};
            f32x4 acc1 = {bv1, bv1, bv1, bv1};
#pragma unroll
            for (int ks = 0; ks < 8; ks++) {
                s16x8 a = *(s16x8*)&A[ks];
                acc0 = __builtin_amdgcn_mfma_f32_16x16x32_bf16(a, *(s16x8*)&B[ks][0], acc0, 0, 0, 0);
                acc1 = __builtin_amdgcn_mfma_f32_16x16x32_bf16(a, *(s16x8*)&B[ks][1], acc1, 0, 0, 0);
            }
            // C/D: col = lane&15, row = quad*4 + reg
            int row0 = nb + rt * 16 + quad * 4;
            int colbase = nt0 * 16 + l15;
#pragma unroll
            for (int reg = 0; reg < 4; reg++) {
                int row = row0 + reg;
                bool ok = row < n;
                if (FUSE1) {
                    float v0 = ok ? acc0[reg] : 0.f;
                    float v1 = ok ? acc1[reg] : 0.f;
                    s0 += v0; ss0 += v0 * v0;
                    s1 += v1; ss1 += v1 * v1;
                    float w0 = __shfl_xor(v0, 1);
                    float w1 = __shfl_xor(v1, 1);
                    if (!(l15 & 1) && ok) {
                        uint* orow = outb + (size_t)row * 64 + nt0 * 8 + (l15 >> 1);
                        orow[0] = pack_bf16(v0, w0);
                        orow[8] = pack_bf16(v1, w1);
                    }
                } else {
                    if (ok) {
                        outf[(size_t)row * D + colbase] = acc0[reg];
                        outf[(size_t)row * D + colbase + 16] = acc1[reg];
                    }
                }
            }
        }
    }
    if (FUSE1) {
        s0 += __shfl_down(s0, 32);  s0 += __shfl_down(s0, 16);
        ss0 += __shfl_down(ss0, 32); ss0 += __shfl_down(ss0, 16);
        s1 += __shfl_down(s1, 32);  s1 += __shfl_down(s1, 16);
        ss1 += __shfl_down(ss1, 32); ss1 += __shfl_down(ss1, 16);
        if (lane < 16) {
            float* pb = pstats + (size_t)blockIdx.x * 256;
            int c0 = nt0 * 16 + l15;
            pb[c0] = s0;       pb[128 + c0] = ss0;
            pb[c0 + 16] = s1;  pb[128 + c0 + 16] = ss1;
        }
    }
}

// ---- the mega kernel: entire pipeline, 9 grid barriers ---------------------
__global__ __launch_bounds__(256, 4) void mega_kernel(MP p)
{
    __shared__ int ism[256];
    __shared__ float scs[256];
    __shared__ int ldflag;
    int G = gridDim.x, bid = blockIdx.x, tid = threadIdx.x;
    int n = p.n, e = p.e;
    int ph = 0;

    // PA: prep xb (bf16 + zero row) & weight frags; degree histogram
    // (cursor + stats + bar zeroed by host memset)
    {
        int ncvt = n * 32;
        int total0 = ncvt + 8192 + 32;
        for (int idx = bid * 256 + tid; idx < total0; idx += G * 256) {
            if (idx < ncvt) {
                float4 v = ((const float4*)p.x)[idx];
                uint2 o;
                o.x = pack_bf16(v.x, v.y);
                o.y = pack_bf16(v.z, v.w);
                ((uint2*)p.xb)[idx] = o;
            } else if (idx < ncvt + 8192) {
                int r = idx - ncvt;
                int layer = r >> 12;
                int rem = r & 4095;
                int lane = rem & 63;
                int knt = rem >> 6;
                int kstep = knt >> 3, nt = knt & 7;
                int nn = nt * 16 + (lane & 15);
                int kbase = kstep * 32 + (lane >> 4) * 8;
                const float* wl = layer ? p.w2l : p.w1l;
                const float* wr = layer ? p.w2r : p.w1r;
                uint* wbp = layer ? p.wb2 : p.wb1;
                float v[8];
#pragma unroll
                for (int j = 0; j < 8; j++) {
                    int k = kbase + j;
                    v[j] = (k < D) ? wl[nn * D + k] : wr[nn * D + (k - D)];
                }
                uint4 o;
                o.x = pack_bf16(v[0], v[1]);
                o.y = pack_bf16(v[2], v[3]);
                o.z = pack_bf16(v[4], v[5]);
                o.w = pack_bf16(v[6], v[7]);
                ((uint4*)wbp)[(kstep * 8 + nt) * 64 + lane] = o;
            } else {
                ((uint2*)p.xb)[ncvt + (idx - ncvt - 8192)] = make_uint2(0, 0);
            }
        }
        for (int i = bid * 256 + tid; i < e; i += G * 256)
            atomicAdd(&p.cursor[p.dst[i]], 1);
    }
    grid_barrier(p.bar, G, ++ph);

    // PB: block-local exclusive scan of degrees; last block scans bsum
    {
        int nsb = (n + 255) >> 8;
        for (int sb = bid; sb < nsb; sb += G) {
            int idx = sb * 256 + tid;
            int v = (idx < n) ? p.cursor[idx] : 0;
            ism[tid] = v;
            __syncthreads();
            for (int off = 1; off < 256; off <<= 1) {
                int u = (tid >= off) ? ism[tid - off] : 0;
                __syncthreads();
                ism[tid] += u;
                __syncthreads();
            }
            if (idx < n) p.rowptr[idx] = ism[tid] - v;
            if (tid == 255) p.bsum[sb] = ism[255];
            __syncthreads();
        }
        if (last_done(p.scanctr, G, &ldflag)) {
            int v = (tid < nsb) ? p.bsum[tid] : 0;
            ism[tid] = v;
            __syncthreads();
            for (int off = 1; off < 256; off <<= 1) {
                int u = (tid >= off) ? ism[tid - off] : 0;
                __syncthreads();
                ism[tid] += u;
                __syncthreads();
            }
            if (tid < nsb) p.bsum[tid] = ism[tid] - v;
            if (tid == 0) p.rowptr[n] = e;
        }
    }
    grid_barrier(p.bar, G, ++ph);

    // PC: add scan-block base; init scatter cursors
    for (int i = bid * 256 + tid; i < n; i += G * 256) {
        int r = p.rowptr[i] + p.bsum[i >> 8];
        p.rowptr[i] = r;
        p.cursor[i] = r;
    }
    grid_barrier(p.bar, G, ++ph);

    // PD: edge scatter into CSR col
    for (int i = bid * 256 + tid; i < e; i += G * 256) {
        int pp = atomicAdd(&p.cursor[p.dst[i]], 1);
        p.col[pp] = p.src[i];
    }
    grid_barrier(p.bar, G, ++ph);

    // PE: agg layer 1
    agg_phase(p.rowptr, p.col, p.xb, p.aggb, n, G);
    grid_barrier(p.bar, G, ++ph);

    // PF: conv layer 1 (+hb pack, +BN partials)
    conv_phase<true>(p.aggb, p.xb, p.wb1, p.b1l, nullptr, p.hb, p.pstats, n, G);
    grid_barrier(p.bar, G, ++ph);

    // PG: reduce BN partials (32 blocks); last of the 32 finalizes scale/shift
    if (bid < 32) {
        int chunk = (G + 31) >> 5;
        int q0 = bid * chunk, q1 = min(q0 + chunk, G);
        float s = 0.f;
        for (int q = q0; q < q1; q++) s += p.pstats[(size_t)q * 256 + tid];
        unsafeAtomicAdd(&p.stats[tid], s);
        if (last_done(p.redctr, 32, &ldflag) && tid < 128) {
            float n_inv = 1.0f / (float)n;
            float sm = atomicAdd(&p.stats[tid], 0.0f);
            float sq = atomicAdd(&p.stats[128 + tid], 0.0f);
            float mean = sm * n_inv;
            float var = fmaxf(sq * n_inv - mean * mean, 0.f);
            float sc = p.gamma[tid] * rsqrtf(var + EPS);
            p.scsh[tid] = sc;
            p.scsh[128 + tid] = p.beta[tid] - mean * sc;
        }
    }
    grid_barrier(p.bar, G, ++ph);

    // PH: bnapply (relu(hb*sc+sh) -> hbn bf16, + zero row)
    {
        scs[tid] = p.scsh[tid];
        __syncthreads();
        int total2 = n * 32;
        for (int idx = bid * 256 + tid; idx < total2; idx += G * 256) {
            int j4 = (idx & 31) * 4;
            uint2 u = ((const uint2*)p.hb)[idx];
            float e0 = fmaxf(bf_lo(u.x) * scs[j4 + 0] + scs[128 + j4 + 0], 0.f);
            float e1 = fmaxf(bf_hi(u.x) * scs[j4 + 1] + scs[128 + j4 + 1], 0.f);
            float e2 = fmaxf(bf_lo(u.y) * scs[j4 + 2] + scs[128 + j4 + 2], 0.f);
            float e3 = fmaxf(bf_hi(u.y) * scs[j4 + 3] + scs[128 + j4 + 3], 0.f);
            uint2 o;
            o.x = pack_bf16(e0, e1);
            o.y = pack_bf16(e2, e3);
            ((uint2*)p.hbn)[idx] = o;
        }
        if (bid == 0 && tid < 32)
            ((uint2*)p.hbn)[total2 + tid] = make_uint2(0, 0);
    }
    grid_barrier(p.bar, G, ++ph);

    // PI: agg layer 2
    agg_phase(p.rowptr, p.col, p.hbn, p.aggb, n, G);
    grid_barrier(p.bar, G, ++ph);

    // PJ: conv layer 2 -> fp32 output
    conv_phase<false>(p.aggb, p.hbn, p.wb2, p.b2l, p.outf, nullptr, nullptr, n, G);
}

extern "C" void kernel_launch(void* const* d_in, const int* in_sizes, int n_in,
                              void* d_out, int out_size, void* d_ws, size_t ws_size,
                              hipStream_t stream)
{
    const float* x     = (const float*)d_in[0];
    const int*   ei    = (const int*)d_in[1];
    const float* w1_l  = (const float*)d_in[2];
    const float* b1_l  = (const float*)d_in[3];
    const float* w1_r  = (const float*)d_in[4];
    const float* w2_l  = (const float*)d_in[5];
    const float* b2_l  = (const float*)d_in[6];
    const float* w2_r  = (const float*)d_in[7];
    const float* gamma = (const float*)d_in[8];
    const float* beta  = (const float*)d_in[9];

    int N = in_sizes[0] / D;
    int E = in_sizes[1] / 2;

    // workspace layout
    uint*  aggb   = (uint*)d_ws;
    uint*  xb     = aggb + (size_t)N * 64;
    uint*  hb     = xb + (size_t)(N + 1) * 64;
    uint*  hbn    = hb + (size_t)N * 64;
    uint*  wb1    = hbn + (size_t)(N + 1) * 64;
    uint*  wb2    = wb1 + 16384;
    float* pstats = (float*)(wb2 + 16384);          // up to 2048 blocks * 256
    float* stats  = pstats + (size_t)2048 * 256;    // 256 (zeroed)
    float* scsh   = stats + 256;                    // 256 (zeroed, harmless)
    int*   bar    = (int*)(scsh + 256);             // 4097 (zeroed)
    int*   scanctr= bar + 4097;                     // (zeroed)
    int*   redctr = bar + 4098;                     // (zeroed)
    int*   cursor = bar + 4100;                     // N (zeroed: degree hist)
    int*   rowptr = cursor + N;                     // N+1
    int*   col    = rowptr + N + 1;                 // E
    int*   bsum   = col + E;                        // 256

    // grid size: blocks/CU from occupancy query (co-residency for the barrier)
    static int g_blocks = 0;
    if (g_blocks == 0) {
        int mb = 0;
        if (hipOccupancyMaxActiveBlocksPerMultiprocessor(&mb, mega_kernel, 256, 0)
                != hipSuccess || mb < 1)
            mb = 1;
        if (mb > 8) mb = 8;
        int cu = 256;
        int dev = 0;
        hipDeviceProp_t prop;
        if (hipGetDevice(&dev) == hipSuccess &&
            hipGetDeviceProperties(&prop, dev) == hipSuccess &&
            prop.multiProcessorCount > 0)
            cu = prop.multiProcessorCount;
        g_blocks = mb * cu;
        if (g_blocks > 2048) g_blocks = 2048;
        if (g_blocks < 64) g_blocks = 64;
    }

    // one memset: stats[256] + scsh[256] + bar/ctrs[4100] + cursor[N]
    hipMemsetAsync(stats, 0, (size_t)(256 + 256 + 4100 + N) * sizeof(int), stream);

    MP p;
    p.x = x; p.w1l = w1_l; p.b1l = b1_l; p.w1r = w1_r;
    p.w2l = w2_l; p.b2l = b2_l; p.w2r = w2_r;
    p.gamma = gamma; p.beta = beta;
    p.src = ei; p.dst = ei + E;
    p.outf = (float*)d_out;
    p.xb = xb; p.aggb = aggb; p.hb = hb; p.hbn = hbn; p.wb1 = wb1; p.wb2 = wb2;
    p.rowptr = rowptr; p.cursor = cursor; p.col = col; p.bsum = bsum;
    p.bar = bar; p.scanctr = scanctr; p.redctr = redctr;
    p.pstats = pstats; p.stats = stats; p.scsh = scsh;
    p.n = N; p.e = E;

    mega_kernel<<<g_blocks, 256, 0, stream>>>(p);
}

// Round 6
// 299.430 us; speedup vs baseline: 3.3092x; 2.2439x over previous
//
#include <hip/hip_runtime.h>

#define D 128
#define EPS 1e-5f
#define FB_EPB 8   // edges per thread in bcount/bscatter (512 thr -> 4096 edges/block)

typedef unsigned int uint;
typedef __attribute__((ext_vector_type(4))) float f32x4;
typedef __attribute__((ext_vector_type(8))) short s16x8;

// ---- bf16 pack/unpack helpers (RTNE) ---------------------------------------
__device__ __forceinline__ uint pack_bf16(float a, float b)
{
    uint ua = __float_as_uint(a);
    uint ub = __float_as_uint(b);
    ua += 0x7FFFu + ((ua >> 16) & 1u);
    ub += 0x7FFFu + ((ub >> 16) & 1u);
    return (ua >> 16) | (ub & 0xFFFF0000u);
}
__device__ __forceinline__ float bf_lo(uint v) { return __uint_as_float(v << 16); }
__device__ __forceinline__ float bf_hi(uint v) { return __uint_as_float(v & 0xFFFF0000u); }

// ---- K1: fused prep (xb, weight frags, zero row) + bcount + bscan tail -----
// blocks [0,nblk): per-(block,bucket) edge counts; the LAST bcount block to
// finish (last-block-done, proven R2/R3) scans bcnt[M] inline (agent-scope
// reads; writes flushed at kernel end). blocks [nblk,..): prep work.
__global__ __launch_bounds__(512) void prep_count_kernel(
    const float* __restrict__ x, uint* __restrict__ xb, int ncvt,
    const float* __restrict__ w1l, const float* __restrict__ w1r,
    const float* __restrict__ w2l, const float* __restrict__ w2r,
    uint* __restrict__ wb1, uint* __restrict__ wb2,
    const int* __restrict__ dst, int* __restrict__ bcnt,
    int E, int nblk, int nbuck, int M, int* __restrict__ scanctr)
{
    __shared__ int cnt[128];
    __shared__ int sums[512];
    __shared__ int lastf;
    int t = threadIdx.x;

    if (blockIdx.x < nblk) {
        // ---- bcount ----
        if (t < 128) cnt[t] = 0;
        __syncthreads();
        int e0 = blockIdx.x * (512 * FB_EPB);
#pragma unroll
        for (int k = 0; k < FB_EPB; k++) {
            int e = e0 + k * 512 + t;
            if (e < E) atomicAdd(&cnt[dst[e] >> 9], 1);
        }
        __syncthreads();
        if (t < nbuck) bcnt[t * nblk + blockIdx.x] = cnt[t];

        // ---- last-block-done: exclusive scan of bcnt[M] ----
        __syncthreads();
        if (t == 0) {
            __threadfence();
            int old = atomicAdd(scanctr, 1);
            lastf = (old == nblk - 1) ? 1 : 0;
            if (lastf) __threadfence();
        }
        __syncthreads();
        if (lastf) {
            int chunk = (M + 511) / 512;
            int b0 = t * chunk;
            int b1 = min(b0 + chunk, M);
            int s = 0;
            for (int i = b0; i < b1; i++)
                s += __hip_atomic_load(&bcnt[i], __ATOMIC_RELAXED,
                                       __HIP_MEMORY_SCOPE_AGENT);
            sums[t] = s;
            __syncthreads();
            for (int off = 1; off < 512; off <<= 1) {
                int u = (t >= off) ? sums[t - off] : 0;
                __syncthreads();
                sums[t] += u;
                __syncthreads();
            }
            int run = sums[t] - s;
            for (int i = b0; i < b1; i++) {
                int v = __hip_atomic_load(&bcnt[i], __ATOMIC_RELAXED,
                                          __HIP_MEMORY_SCOPE_AGENT);
                bcnt[i] = run;
                run += v;
            }
            if (t == 511) bcnt[M] = sums[511];
        }
    } else {
        // ---- prep ----
        int idx = (blockIdx.x - nblk) * 512 + t;
        if (idx < ncvt) {
            float4 v = ((const float4*)x)[idx];
            uint2 o;
            o.x = pack_bf16(v.x, v.y);
            o.y = pack_bf16(v.z, v.w);
            ((uint2*)xb)[idx] = o;
        } else if (idx < ncvt + 8192) {
            int r = idx - ncvt;          // 0..8191
            int layer = r >> 12;
            int rem = r & 4095;
            int lane = rem & 63;
            int knt = rem >> 6;
            int kstep = knt >> 3, nt = knt & 7;
            int nn = nt * 16 + (lane & 15);
            int kbase = kstep * 32 + (lane >> 4) * 8;
            const float* wl = layer ? w2l : w1l;
            const float* wr = layer ? w2r : w1r;
            uint* wb = layer ? wb2 : wb1;
            float v[8];
#pragma unroll
            for (int j = 0; j < 8; j++) {
                int k = kbase + j;
                v[j] = (k < D) ? wl[nn * D + k] : wr[nn * D + (k - D)];
            }
            uint4 o;
            o.x = pack_bf16(v[0], v[1]);
            o.y = pack_bf16(v[2], v[3]);
            o.z = pack_bf16(v[4], v[5]);
            o.w = pack_bf16(v[6], v[7]);
            ((uint4*)wb)[(kstep * 8 + nt) * 64 + lane] = o;
        } else if (idx < ncvt + 8192 + 32) {
            // zero row (index N) for invalid-slot gathers in agg1
            ((uint2*)xb)[ncvt + (idx - ncvt - 8192)] = make_uint2(0, 0);
        }
    }
}

// ---- radix CSR phase 3: scatter edges into bucket-contiguous ebuf ----------
__global__ __launch_bounds__(512) void bscatter_kernel(const int* __restrict__ src,
                                                       const int* __restrict__ dst,
                                                       const int* __restrict__ bcnt,
                                                       uint2* __restrict__ ebuf,
                                                       int E, int nblk, int nbuck)
{
    __shared__ int cnt[128], base[128];
    int t = threadIdx.x;
    if (t < 128) cnt[t] = 0;
    __syncthreads();
    int e0 = blockIdx.x * (512 * FB_EPB);
    int s[FB_EPB], d[FB_EPB], loc[FB_EPB];
#pragma unroll
    for (int k = 0; k < FB_EPB; k++) {
        int e = e0 + k * 512 + t;
        if (e < E) {
            s[k] = src[e];
            d[k] = dst[e];
            loc[k] = atomicAdd(&cnt[d[k] >> 9], 1);
        }
    }
    __syncthreads();
    if (t < nbuck) base[t] = bcnt[t * nblk + blockIdx.x];
    __syncthreads();
#pragma unroll
    for (int k = 0; k < FB_EPB; k++) {
        int e = e0 + k * 512 + t;
        if (e < E) {
            int b = d[k] >> 9;
            ebuf[base[b] + loc[k]] = make_uint2((uint)s[k], (uint)d[k]);
        }
    }
}

// ---- radix CSR phase 4: per-bucket build rowptr + col (LDS only) -----------
__global__ __launch_bounds__(512) void pbuild_kernel(const int* __restrict__ bcnt,
                                                     const uint2* __restrict__ ebuf,
                                                     int* __restrict__ rowptr,
                                                     int* __restrict__ col,
                                                     int n, int nblk, int nbuck, int M, int E)
{
    __shared__ int lcnt[512], lscan[512];
    int t = threadIdx.x;
    int b = blockIdx.x;
    int nb = b << 9;
    int e0 = bcnt[b * nblk];
    int e1 = (b + 1 < nbuck) ? bcnt[(b + 1) * nblk] : bcnt[M];
    lcnt[t] = 0;
    __syncthreads();
    for (int i = e0 + t; i < e1; i += 512)
        atomicAdd(&lcnt[(int)ebuf[i].y - nb], 1);
    __syncthreads();
    int s = lcnt[t];
    lscan[t] = s;
    __syncthreads();
    for (int off = 1; off < 512; off <<= 1) {
        int u = (t >= off) ? lscan[t - off] : 0;
        __syncthreads();
        lscan[t] += u;
        __syncthreads();
    }
    int start = e0 + lscan[t] - s;
    int ncnt = min(512, n - nb);
    if (t < ncnt) rowptr[nb + t] = start;
    if (b == nbuck - 1 && t == 0) rowptr[n] = E;
    lscan[t] = start;
    __syncthreads();
    for (int i = e0 + t; i < e1; i += 512) {
        uint2 ed = ebuf[i];
        int p = atomicAdd(&lscan[(int)ed.y - nb], 1);
        col[p] = (int)ed.x;
    }
}

// ---- agg layer 1: wave per node, 16-slot batches, zero-row padding ---------
__global__ __launch_bounds__(256) void agg_kernel(const int* __restrict__ rowptr,
                                                  const int* __restrict__ col,
                                                  const uint* __restrict__ featb,
                                                  uint* __restrict__ aggb, int n)
{
    int node = blockIdx.x * 4 + (threadIdx.x >> 6);
    if (node >= n) return;
    int lane = threadIdx.x & 63;
    int sub = lane >> 4, l16 = lane & 15;
    int r0 = rowptr[node], r1 = rowptr[node + 1];
    uint4* out4 = (uint4*)aggb;
    if (r0 == r1) {
        if (lane < 16) out4[(size_t)node * 16 + l16] = make_uint4(0, 0, 0, 0);
        return;
    }
    float acc[8] = {0.f, 0.f, 0.f, 0.f, 0.f, 0.f, 0.f, 0.f};
    const uint4* fb = (const uint4*)featb;
    int last = r1 - 1;

    for (int i = r0; i < r1; i += 16) {
        uint4 v[4];
#pragma unroll
        for (int r = 0; r < 4; r++) {
            int idx = i + r * 4 + sub;
            int cl = col[min(idx, last)];
            int c = (idx < r1) ? cl : n;       // n = zero row
            v[r] = fb[(size_t)c * 16 + l16];
        }
#pragma unroll
        for (int r = 0; r < 4; r++) {
            uint4 u = v[r];
            acc[0] += bf_lo(u.x); acc[1] += bf_hi(u.x);
            acc[2] += bf_lo(u.y); acc[3] += bf_hi(u.y);
            acc[4] += bf_lo(u.z); acc[5] += bf_hi(u.z);
            acc[6] += bf_lo(u.w); acc[7] += bf_hi(u.w);
        }
    }
#pragma unroll
    for (int j = 0; j < 8; j++) {
        acc[j] += __shfl_down(acc[j], 32);
        acc[j] += __shfl_down(acc[j], 16);
    }
    if (lane < 16) {
        float inv = 1.0f / (float)(r1 - r0);
        uint4 o;
        o.x = pack_bf16(acc[0] * inv, acc[1] * inv);
        o.y = pack_bf16(acc[2] * inv, acc[3] * inv);
        o.z = pack_bf16(acc[4] * inv, acc[5] * inv);
        o.w = pack_bf16(acc[6] * inv, acc[7] * inv);
        out4[(size_t)node * 16 + l16] = o;
    }
}

// ---- agg layer 2 + fused BN/ReLU (replaces bnapply kernel) -----------------
// Gathers hb (pre-BN bf16), applies z = relu(hb*sc+sh) per gathered element
// in fp32, accumulates with a validity mask (no zero row needed), and also
// writes the bf16 hbn root row for this node (consumed by conv2's lin_r).
__global__ __launch_bounds__(256) void aggbn_kernel(const int* __restrict__ rowptr,
                                                    const int* __restrict__ col,
                                                    const uint* __restrict__ hb,
                                                    uint* __restrict__ aggb,
                                                    uint* __restrict__ hbn,
                                                    const float* __restrict__ scsh, int n)
{
    int node = blockIdx.x * 4 + (threadIdx.x >> 6);
    if (node >= n) return;
    int lane = threadIdx.x & 63;
    int sub = lane >> 4, l16 = lane & 15;
    const uint4* fb = (const uint4*)hb;
    uint4* out4 = (uint4*)aggb;
    uint4* hbn4 = (uint4*)hbn;

    // BN params for this lane's 8-feature chunk
    float4 sca = *(const float4*)&scsh[l16 * 8];
    float4 scb = *(const float4*)&scsh[l16 * 8 + 4];
    float4 sha = *(const float4*)&scsh[128 + l16 * 8];
    float4 shb = *(const float4*)&scsh[128 + l16 * 8 + 4];
    float sc[8] = {sca.x, sca.y, sca.z, sca.w, scb.x, scb.y, scb.z, scb.w};
    float sh[8] = {sha.x, sha.y, sha.z, sha.w, shb.x, shb.y, shb.z, shb.w};

    // root row: hbn = relu(bn(hb[node])) in bf16 (lane<16 covers the row)
    if (lane < 16) {
        uint4 u = fb[(size_t)node * 16 + l16];
        float e0 = fmaxf(fmaf(bf_lo(u.x), sc[0], sh[0]), 0.f);
        float e1 = fmaxf(fmaf(bf_hi(u.x), sc[1], sh[1]), 0.f);
        float e2 = fmaxf(fmaf(bf_lo(u.y), sc[2], sh[2]), 0.f);
        float e3 = fmaxf(fmaf(bf_hi(u.y), sc[3], sh[3]), 0.f);
        float e4 = fmaxf(fmaf(bf_lo(u.z), sc[4], sh[4]), 0.f);
        float e5 = fmaxf(fmaf(bf_hi(u.z), sc[5], sh[5]), 0.f);
        float e6 = fmaxf(fmaf(bf_lo(u.w), sc[6], sh[6]), 0.f);
        float e7 = fmaxf(fmaf(bf_hi(u.w), sc[7], sh[7]), 0.f);
        uint4 o;
        o.x = pack_bf16(e0, e1);
        o.y = pack_bf16(e2, e3);
        o.z = pack_bf16(e4, e5);
        o.w = pack_bf16(e6, e7);
        hbn4[(size_t)node * 16 + l16] = o;
    }

    int r0 = rowptr[node], r1 = rowptr[node + 1];
    if (r0 == r1) {
        if (lane < 16) out4[(size_t)node * 16 + l16] = make_uint4(0, 0, 0, 0);
        return;
    }
    float acc[8] = {0.f, 0.f, 0.f, 0.f, 0.f, 0.f, 0.f, 0.f};
    int last = r1 - 1;

    for (int i = r0; i < r1; i += 16) {
        uint4 v[4];
        float m[4];
#pragma unroll
        for (int r = 0; r < 4; r++) {
            int idx = i + r * 4 + sub;
            int cl = col[min(idx, last)];      // pad slots re-gather a valid row
            m[r] = (idx < r1) ? 1.f : 0.f;     // ...and are masked out here
            v[r] = fb[(size_t)cl * 16 + l16];
        }
#pragma unroll
        for (int r = 0; r < 4; r++) {
            uint4 u = v[r];
            float mr = m[r];
            acc[0] = fmaf(mr, fmaxf(fmaf(bf_lo(u.x), sc[0], sh[0]), 0.f), acc[0]);
            acc[1] = fmaf(mr, fmaxf(fmaf(bf_hi(u.x), sc[1], sh[1]), 0.f), acc[1]);
            acc[2] = fmaf(mr, fmaxf(fmaf(bf_lo(u.y), sc[2], sh[2]), 0.f), acc[2]);
            acc[3] = fmaf(mr, fmaxf(fmaf(bf_hi(u.y), sc[3], sh[3]), 0.f), acc[3]);
            acc[4] = fmaf(mr, fmaxf(fmaf(bf_lo(u.z), sc[4], sh[4]), 0.f), acc[4]);
            acc[5] = fmaf(mr, fmaxf(fmaf(bf_hi(u.z), sc[5], sh[5]), 0.f), acc[5]);
            acc[6] = fmaf(mr, fmaxf(fmaf(bf_lo(u.w), sc[6], sh[6]), 0.f), acc[6]);
            acc[7] = fmaf(mr, fmaxf(fmaf(bf_hi(u.w), sc[7], sh[7]), 0.f), acc[7]);
        }
    }
#pragma unroll
    for (int j = 0; j < 8; j++) {
        acc[j] += __shfl_down(acc[j], 32);
        acc[j] += __shfl_down(acc[j], 16);
    }
    if (lane < 16) {
        float inv = 1.0f / (float)(r1 - r0);
        uint4 o;
        o.x = pack_bf16(acc[0] * inv, acc[1] * inv);
        o.y = pack_bf16(acc[2] * inv, acc[3] * inv);
        o.z = pack_bf16(acc[4] * inv, acc[5] * inv);
        o.w = pack_bf16(acc[6] * inv, acc[7] * inv);
        out4[(size_t)node * 16 + l16] = o;
    }
}

// ---- MFMA conv (R0-proven LDS-tile version) --------------------------------
// FUSE1: write bf16 hb + per-block BN-stat partials (plain stores, NO atomics)
#define TSTRIDE 132
template<bool FUSE1>
__global__ __launch_bounds__(256) void conv_kernel(
    const uint* __restrict__ p1b, const uint* __restrict__ p2b,
    const uint* __restrict__ wb, const float* __restrict__ bias,
    float* __restrict__ outf, uint* __restrict__ outb,
    float* __restrict__ pstats, int n)
{
    extern __shared__ float smem[];   // FUSE1: tile[64][TSTRIDE]
    float* tile = smem;
    int w = threadIdx.x >> 6, lane = threadIdx.x & 63;
    int quad = lane >> 4, l15 = lane & 15;
    int nb = blockIdx.x * 64;

    const uint4* p1 = (const uint4*)p1b;
    const uint4* p2 = (const uint4*)p2b;
    const uint4* wv = (const uint4*)wb;

    uint4 B[8][2];
    int nt0 = w * 2;
#pragma unroll
    for (int ks = 0; ks < 8; ks++) {
#pragma unroll
        for (int t = 0; t < 2; t++)
            B[ks][t] = wv[(ks * 8 + nt0 + t) * 64 + lane];
    }

    float bv0 = bias[nt0 * 16 + l15];
    float bv1 = bias[nt0 * 16 + 16 + l15];

    for (int rt = 0; rt < 4; rt++) {
        int node = nb + rt * 16 + l15;
        int nc = min(node, n - 1);
        uint4 A[8];
#pragma unroll
        for (int ks = 0; ks < 4; ks++) A[ks] = p1[(size_t)nc * 16 + ks * 4 + quad];
#pragma unroll
        for (int ks = 0; ks < 4; ks++) A[ks + 4] = p2[(size_t)nc * 16 + ks * 4 + quad];

        f32x4 acc0 = {bv0, bv0, bv0, bv0};
        f32x4 acc1 = {bv1, bv1, bv1, bv1};
#pragma unroll
        for (int ks = 0; ks < 8; ks++) {
            s16x8 a = *(s16x8*)&A[ks];
            acc0 = __builtin_amdgcn_mfma_f32_16x16x32_bf16(a, *(s16x8*)&B[ks][0], acc0, 0, 0, 0);
            acc1 = __builtin_amdgcn_mfma_f32_16x16x32_bf16(a, *(s16x8*)&B[ks][1], acc1, 0, 0, 0);
        }
        // C/D: col = lane&15, row = quad*4 + reg
        int row0 = nb + rt * 16 + quad * 4;
        int colbase = nt0 * 16 + l15;
        if (FUSE1) {
            int rloc0 = rt * 16 + quad * 4;
#pragma unroll
            for (int reg = 0; reg < 4; reg++) {
                bool ok = (row0 + reg) < n;
                tile[(rloc0 + reg) * TSTRIDE + colbase]      = ok ? acc0[reg] : 0.f;
                tile[(rloc0 + reg) * TSTRIDE + colbase + 16] = ok ? acc1[reg] : 0.f;
            }
        } else {
#pragma unroll
            for (int reg = 0; reg < 4; reg++) {
                int row = row0 + reg;
                if (row < n) {
                    outf[(size_t)row * D + colbase] = acc0[reg];
                    outf[(size_t)row * D + colbase + 16] = acc1[reg];
                }
            }
        }
    }

    if (FUSE1) {
        __syncthreads();
        int colj = threadIdx.x & 127, half = threadIdx.x >> 7;
        float s = 0.f, ss = 0.f;
        for (int r = half * 32; r < half * 32 + 32; r++) {
            float v = tile[r * TSTRIDE + colj];
            s += v;
            ss += v * v;
        }
        float* pb = pstats + (size_t)blockIdx.x * 512 + half * 256;
        pb[colj] = s;
        pb[128 + colj] = ss;
        uint4* ob4 = (uint4*)outb;
#pragma unroll
        for (int q4 = 0; q4 < 4; q4++) {
            int idx = q4 * 256 + threadIdx.x;
            int r = idx >> 4, q = idx & 15;
            int row = nb + r;
            if (row < n) {
                float* tr = &tile[r * TSTRIDE + q * 8];
                uint4 o;
                o.x = pack_bf16(tr[0], tr[1]);
                o.y = pack_bf16(tr[2], tr[3]);
                o.z = pack_bf16(tr[4], tr[5]);
                o.w = pack_bf16(tr[6], tr[7]);
                ob4[(size_t)row * 16 + q] = o;
            }
        }
    }
}

// ---- fused reduce + BN finalize: 32 blocks, last-block-done computes scsh --
__global__ __launch_bounds__(256) void reduce_kernel(const float* __restrict__ pstats,
                                                     float* __restrict__ stats,
                                                     int* __restrict__ ctr,
                                                     const float* __restrict__ gamma,
                                                     const float* __restrict__ beta,
                                                     float* __restrict__ scsh,
                                                     int nparts, float n_inv)
{
    __shared__ int lastf;
    int j = threadIdx.x;
    int chunk = (nparts + gridDim.x - 1) / gridDim.x;
    int p0 = blockIdx.x * chunk;
    int p1 = min(p0 + chunk, nparts);
    float s = 0.f;
    for (int p = p0; p < p1; p++) s += pstats[(size_t)p * 256 + j];
    unsafeAtomicAdd(&stats[j], s);   // 32 adds/address total: negligible contention
    __threadfence();
    __syncthreads();
    if (threadIdx.x == 0) {
        int old = atomicAdd(ctr, 1);
        lastf = (old == (int)gridDim.x - 1) ? 1 : 0;
    }
    __syncthreads();
    if (lastf && j < 128) {
        float sm = atomicAdd(&stats[j], 0.0f);        // device-scope read
        float sq = atomicAdd(&stats[128 + j], 0.0f);
        float mean = sm * n_inv;
        float var = fmaxf(sq * n_inv - mean * mean, 0.f);
        float sc = gamma[j] * rsqrtf(var + EPS);
        scsh[j] = sc;
        scsh[128 + j] = beta[j] - mean * sc;
    }
}

extern "C" void kernel_launch(void* const* d_in, const int* in_sizes, int n_in,
                              void* d_out, int out_size, void* d_ws, size_t ws_size,
                              hipStream_t stream)
{
    const float* x     = (const float*)d_in[0];
    const int*   ei    = (const int*)d_in[1];
    const float* w1_l  = (const float*)d_in[2];
    const float* b1_l  = (const float*)d_in[3];
    const float* w1_r  = (const float*)d_in[4];
    const float* w2_l  = (const float*)d_in[5];
    const float* b2_l  = (const float*)d_in[6];
    const float* w2_r  = (const float*)d_in[7];
    const float* gamma = (const float*)d_in[8];
    const float* beta  = (const float*)d_in[9];

    int N = in_sizes[0] / D;
    int E = in_sizes[1] / 2;
    const int* src = ei;
    const int* dst = ei + E;

    int cblocks = (N + 63) / 64;
    int nbuck   = (N + 511) >> 9;               // 98
    int nblk    = (E + 4095) / 4096;            // 196
    int M       = nbuck * nblk;                 // 19208

    // workspace layout:
    // uints: aggb[N*64] | xb[(N+1)*64] | hb[N*64] | hbn[N*64] | wb1/wb2
    // uint2: ebuf[E]; floats: stats[256]|scanctr|redctr|scsh[256]|pstats
    // ints: rowptr|col|bcnt
    uint*  aggb   = (uint*)d_ws;
    uint*  xb     = aggb + (size_t)N * 64;
    uint*  hb     = xb + (size_t)(N + 1) * 64;
    uint*  hbn    = hb + (size_t)N * 64;
    uint*  wb1    = hbn + (size_t)N * 64;
    uint*  wb2    = wb1 + 16384;
    uint2* ebuf   = (uint2*)(wb2 + 16384);
    float* stats  = (float*)(ebuf + E);
    int*   scanctr= (int*)(stats + 256);
    int*   redctr = scanctr + 1;
    float* scsh   = stats + 258;
    float* pstats = scsh + 256;
    int*   rowptr = (int*)(pstats + (size_t)cblocks * 512);
    int*   col    = rowptr + N + 1;
    int*   bcnt   = col + E;

    // zero stats[256] + scanctr + redctr in one small memset
    hipMemsetAsync(stats, 0, 258 * sizeof(float), stream);

    // K1: fused prep + bcount + bscan tail
    int ncvt = N * 32;
    int total0 = ncvt + 8192 + 32;
    int pblocks = (total0 + 511) / 512;
    prep_count_kernel<<<nblk + pblocks, 512, 0, stream>>>(
        x, xb, ncvt, w1_l, w1_r, w2_l, w2_r, wb1, wb2,
        dst, bcnt, E, nblk, nbuck, M, scanctr);

    // K2/K3: finish CSR build
    bscatter_kernel<<<nblk, 512, 0, stream>>>(src, dst, bcnt, ebuf, E, nblk, nbuck);
    pbuild_kernel<<<nbuck, 512, 0, stream>>>(bcnt, ebuf, rowptr, col, N, nblk, nbuck, M, E);

    int ablocks = (N + 3) / 4;

    // K4/K5: layer 1
    agg_kernel<<<ablocks, 256, 0, stream>>>(rowptr, col, xb, aggb, N);
    conv_kernel<true><<<cblocks, 256, 64 * TSTRIDE * 4, stream>>>(
        aggb, xb, wb1, b1_l, nullptr, hb, pstats, N);

    // K6: BN reduce + finalize
    reduce_kernel<<<32, 256, 0, stream>>>(pstats, stats, redctr, gamma, beta, scsh,
                                          cblocks * 2, 1.0f / (float)N);

    // K7: agg layer 2 with fused BN/ReLU (also emits hbn root rows)
    aggbn_kernel<<<ablocks, 256, 0, stream>>>(rowptr, col, hb, aggb, hbn, scsh, N);

    // K8: conv layer 2 -> fp32 output
    conv_kernel<false><<<cblocks, 256, 1024, stream>>>(
        aggb, hbn, wb2, b2_l, (float*)d_out, nullptr, nullptr, N);
}

// Round 8
// 261.754 us; speedup vs baseline: 3.7856x; 1.1439x over previous
//
#include <hip/hip_runtime.h>

#define D 128
#define EPS 1e-5f
#define FB_EPB 8   // edges per thread in bcount/bscatter (512 thr -> 4096 edges/block)

typedef unsigned int uint;
typedef __attribute__((ext_vector_type(4))) float f32x4;
typedef __attribute__((ext_vector_type(8))) short s16x8;

// ---- bf16 pack/unpack helpers (RTNE) ---------------------------------------
__device__ __forceinline__ uint pack_bf16(float a, float b)
{
    uint ua = __float_as_uint(a);
    uint ub = __float_as_uint(b);
    ua += 0x7FFFu + ((ua >> 16) & 1u);
    ub += 0x7FFFu + ((ub >> 16) & 1u);
    return (ua >> 16) | (ub & 0xFFFF0000u);
}
__device__ __forceinline__ float bf_lo(uint v) { return __uint_as_float(v << 16); }
__device__ __forceinline__ float bf_hi(uint v) { return __uint_as_float(v & 0xFFFF0000u); }

// ---- K1: prep (xb, weight frags, zero row, zero stats) || bcount -----------
// Pure block-range fusion of two INDEPENDENT kernels. NO cross-block data
// handoff inside the kernel (R6 lesson: intra-kernel handoff needs device-
// scope loads at LLC latency; kernel boundaries flush for free).
__global__ __launch_bounds__(512) void prep_count_kernel(
    const float* __restrict__ x, uint* __restrict__ xb, int ncvt,
    const float* __restrict__ w1l, const float* __restrict__ w1r,
    const float* __restrict__ w2l, const float* __restrict__ w2r,
    uint* __restrict__ wb1, uint* __restrict__ wb2,
    const int* __restrict__ dst, int* __restrict__ bcnt,
    float* __restrict__ stats,
    int E, int nblk, int nbuck)
{
    __shared__ int cnt[128];
    int t = threadIdx.x;

    if (blockIdx.x < (uint)nblk) {
        // ---- bcount ----
        if (t < 128) cnt[t] = 0;
        __syncthreads();
        int e0 = blockIdx.x * (512 * FB_EPB);
#pragma unroll
        for (int k = 0; k < FB_EPB; k++) {
            int e = e0 + k * 512 + t;
            if (e < E) atomicAdd(&cnt[dst[e] >> 9], 1);
        }
        __syncthreads();
        if (t < nbuck) bcnt[t * nblk + blockIdx.x] = cnt[t];
    } else {
        // ---- prep ----
        if (blockIdx.x == (uint)nblk && t < 258) stats[t] = 0.f;  // stats+ctrs
        int idx = (blockIdx.x - nblk) * 512 + t;
        if (idx < ncvt) {
            float4 v = ((const float4*)x)[idx];
            uint2 o;
            o.x = pack_bf16(v.x, v.y);
            o.y = pack_bf16(v.z, v.w);
            ((uint2*)xb)[idx] = o;
        } else if (idx < ncvt + 8192) {
            int r = idx - ncvt;          // 0..8191
            int layer = r >> 12;
            int rem = r & 4095;
            int lane = rem & 63;
            int knt = rem >> 6;
            int kstep = knt >> 3, nt = knt & 7;
            int nn = nt * 16 + (lane & 15);
            int kbase = kstep * 32 + (lane >> 4) * 8;
            const float* wl = layer ? w2l : w1l;
            const float* wr = layer ? w2r : w1r;
            uint* wb = layer ? wb2 : wb1;
            float v[8];
#pragma unroll
            for (int j = 0; j < 8; j++) {
                int k = kbase + j;
                v[j] = (k < D) ? wl[nn * D + k] : wr[nn * D + (k - D)];
            }
            uint4 o;
            o.x = pack_bf16(v[0], v[1]);
            o.y = pack_bf16(v[2], v[3]);
            o.z = pack_bf16(v[4], v[5]);
            o.w = pack_bf16(v[6], v[7]);
            ((uint4*)wb)[(kstep * 8 + nt) * 64 + lane] = o;
        } else if (idx < ncvt + 8192 + 32) {
            // zero row (index N) for invalid-slot gathers in agg1
            ((uint2*)xb)[ncvt + (idx - ncvt - 8192)] = make_uint2(0, 0);
        }
    }
}

// ---- radix CSR phase 2: single-block exclusive scan of bcnt[M], append total
// (own kernel on purpose: normal cached loads after the K1 boundary flush)
__global__ __launch_bounds__(1024) void bscan_kernel(int* __restrict__ bcnt, int M)
{
    __shared__ int sums[1024];
    int t = threadIdx.x;
    int chunk = (M + 1023) / 1024;
    int b0 = t * chunk;
    int b1 = min(b0 + chunk, M);
    int s = 0;
    for (int i = b0; i < b1; i++) s += bcnt[i];
    sums[t] = s;
    __syncthreads();
    for (int off = 1; off < 1024; off <<= 1) {
        int u = (t >= off) ? sums[t - off] : 0;
        __syncthreads();
        sums[t] += u;
        __syncthreads();
    }
    int run = sums[t] - s;
    for (int i = b0; i < b1; i++) { int v = bcnt[i]; bcnt[i] = run; run += v; }
    if (t == 1023) bcnt[M] = sums[1023];
}

// ---- radix CSR phase 3: scatter edges into bucket-contiguous ebuf ----------
__global__ __launch_bounds__(512) void bscatter_kernel(const int* __restrict__ src,
                                                       const int* __restrict__ dst,
                                                       const int* __restrict__ bcnt,
                                                       uint2* __restrict__ ebuf,
                                                       int E, int nblk, int nbuck)
{
    __shared__ int cnt[128], base[128];
    int t = threadIdx.x;
    if (t < 128) cnt[t] = 0;
    __syncthreads();
    int e0 = blockIdx.x * (512 * FB_EPB);
    int s[FB_EPB], d[FB_EPB], loc[FB_EPB];
#pragma unroll
    for (int k = 0; k < FB_EPB; k++) {
        int e = e0 + k * 512 + t;
        if (e < E) {
            s[k] = src[e];
            d[k] = dst[e];
            loc[k] = atomicAdd(&cnt[d[k] >> 9], 1);
        }
    }
    __syncthreads();
    if (t < nbuck) base[t] = bcnt[t * nblk + blockIdx.x];
    __syncthreads();
#pragma unroll
    for (int k = 0; k < FB_EPB; k++) {
        int e = e0 + k * 512 + t;
        if (e < E) {
            int b = d[k] >> 9;
            ebuf[base[b] + loc[k]] = make_uint2((uint)s[k], (uint)d[k]);
        }
    }
}

// ---- radix CSR phase 4: per-bucket build rowptr + col (LDS only) -----------
__global__ __launch_bounds__(512) void pbuild_kernel(const int* __restrict__ bcnt,
                                                     const uint2* __restrict__ ebuf,
                                                     int* __restrict__ rowptr,
                                                     int* __restrict__ col,
                                                     int n, int nblk, int nbuck, int M, int E)
{
    __shared__ int lcnt[512], lscan[512];
    int t = threadIdx.x;
    int b = blockIdx.x;
    int nb = b << 9;
    int e0 = bcnt[b * nblk];
    int e1 = (b + 1 < nbuck) ? bcnt[(b + 1) * nblk] : bcnt[M];
    lcnt[t] = 0;
    __syncthreads();
    for (int i = e0 + t; i < e1; i += 512)
        atomicAdd(&lcnt[(int)ebuf[i].y - nb], 1);
    __syncthreads();
    int s = lcnt[t];
    lscan[t] = s;
    __syncthreads();
    for (int off = 1; off < 512; off <<= 1) {
        int u = (t >= off) ? lscan[t - off] : 0;
        __syncthreads();
        lscan[t] += u;
        __syncthreads();
    }
    int start = e0 + lscan[t] - s;
    int ncnt = min(512, n - nb);
    if (t < ncnt) rowptr[nb + t] = start;
    if (b == nbuck - 1 && t == 0) rowptr[n] = E;
    lscan[t] = start;
    __syncthreads();
    for (int i = e0 + t; i < e1; i += 512) {
        uint2 ed = ebuf[i];
        int p = atomicAdd(&lscan[(int)ed.y - nb], 1);
        col[p] = (int)ed.x;
    }
}

// ---- agg layer 1: wave per node, 16-slot batches, zero-row padding ---------
__global__ __launch_bounds__(256) void agg_kernel(const int* __restrict__ rowptr,
                                                  const int* __restrict__ col,
                                                  const uint* __restrict__ featb,
                                                  uint* __restrict__ aggb, int n)
{
    int node = blockIdx.x * 4 + (threadIdx.x >> 6);
    if (node >= n) return;
    int lane = threadIdx.x & 63;
    int sub = lane >> 4, l16 = lane & 15;
    int r0 = rowptr[node], r1 = rowptr[node + 1];
    uint4* out4 = (uint4*)aggb;
    if (r0 == r1) {
        if (lane < 16) out4[(size_t)node * 16 + l16] = make_uint4(0, 0, 0, 0);
        return;
    }
    float acc[8] = {0.f, 0.f, 0.f, 0.f, 0.f, 0.f, 0.f, 0.f};
    const uint4* fb = (const uint4*)featb;
    int last = r1 - 1;

    for (int i = r0; i < r1; i += 16) {
        uint4 v[4];
#pragma unroll
        for (int r = 0; r < 4; r++) {
            int idx = i + r * 4 + sub;
            int cl = col[min(idx, last)];
            int c = (idx < r1) ? cl : n;       // n = zero row
            v[r] = fb[(size_t)c * 16 + l16];
        }
#pragma unroll
        for (int r = 0; r < 4; r++) {
            uint4 u = v[r];
            acc[0] += bf_lo(u.x); acc[1] += bf_hi(u.x);
            acc[2] += bf_lo(u.y); acc[3] += bf_hi(u.y);
            acc[4] += bf_lo(u.z); acc[5] += bf_hi(u.z);
            acc[6] += bf_lo(u.w); acc[7] += bf_hi(u.w);
        }
    }
#pragma unroll
    for (int j = 0; j < 8; j++) {
        acc[j] += __shfl_down(acc[j], 32);
        acc[j] += __shfl_down(acc[j], 16);
    }
    if (lane < 16) {
        float inv = 1.0f / (float)(r1 - r0);
        uint4 o;
        o.x = pack_bf16(acc[0] * inv, acc[1] * inv);
        o.y = pack_bf16(acc[2] * inv, acc[3] * inv);
        o.z = pack_bf16(acc[4] * inv, acc[5] * inv);
        o.w = pack_bf16(acc[6] * inv, acc[7] * inv);
        out4[(size_t)node * 16 + l16] = o;
    }
}

// ---- agg layer 2 + fused BN/ReLU (replaces bnapply kernel) -----------------
// Gathers hb (pre-BN bf16), applies z = relu(hb*sc+sh) per gathered element
// in fp32, accumulates with a validity mask, and also writes the bf16 hbn
// root row for this node (consumed by conv2's lin_r).
__global__ __launch_bounds__(256) void aggbn_kernel(const int* __restrict__ rowptr,
                                                    const int* __restrict__ col,
                                                    const uint* __restrict__ hb,
                                                    uint* __restrict__ aggb,
                                                    uint* __restrict__ hbn,
                                                    const float* __restrict__ scsh, int n)
{
    int node = blockIdx.x * 4 + (threadIdx.x >> 6);
    if (node >= n) return;
    int lane = threadIdx.x & 63;
    int sub = lane >> 4, l16 = lane & 15;
    const uint4* fb = (const uint4*)hb;
    uint4* out4 = (uint4*)aggb;
    uint4* hbn4 = (uint4*)hbn;

    // BN params for this lane's 8-feature chunk
    float4 sca = *(const float4*)&scsh[l16 * 8];
    float4 scb = *(const float4*)&scsh[l16 * 8 + 4];
    float4 sha = *(const float4*)&scsh[128 + l16 * 8];
    float4 shb = *(const float4*)&scsh[128 + l16 * 8 + 4];
    float sc[8] = {sca.x, sca.y, sca.z, sca.w, scb.x, scb.y, scb.z, scb.w};
    float sh[8] = {sha.x, sha.y, sha.z, sha.w, shb.x, shb.y, shb.z, shb.w};

    // root row: hbn = relu(bn(hb[node])) in bf16 (lane<16 covers the row)
    if (lane < 16) {
        uint4 u = fb[(size_t)node * 16 + l16];
        float e0 = fmaxf(fmaf(bf_lo(u.x), sc[0], sh[0]), 0.f);
        float e1 = fmaxf(fmaf(bf_hi(u.x), sc[1], sh[1]), 0.f);
        float e2 = fmaxf(fmaf(bf_lo(u.y), sc[2], sh[2]), 0.f);
        float e3 = fmaxf(fmaf(bf_hi(u.y), sc[3], sh[3]), 0.f);
        float e4 = fmaxf(fmaf(bf_lo(u.z), sc[4], sh[4]), 0.f);
        float e5 = fmaxf(fmaf(bf_hi(u.z), sc[5], sh[5]), 0.f);
        float e6 = fmaxf(fmaf(bf_lo(u.w), sc[6], sh[6]), 0.f);
        float e7 = fmaxf(fmaf(bf_hi(u.w), sc[7], sh[7]), 0.f);
        uint4 o;
        o.x = pack_bf16(e0, e1);
        o.y = pack_bf16(e2, e3);
        o.z = pack_bf16(e4, e5);
        o.w = pack_bf16(e6, e7);
        hbn4[(size_t)node * 16 + l16] = o;
    }

    int r0 = rowptr[node], r1 = rowptr[node + 1];
    if (r0 == r1) {
        if (lane < 16) out4[(size_t)node * 16 + l16] = make_uint4(0, 0, 0, 0);
        return;
    }
    float acc[8] = {0.f, 0.f, 0.f, 0.f, 0.f, 0.f, 0.f, 0.f};
    int last = r1 - 1;

    for (int i = r0; i < r1; i += 16) {
        uint4 v[4];
        float m[4];
#pragma unroll
        for (int r = 0; r < 4; r++) {
            int idx = i + r * 4 + sub;
            int cl = col[min(idx, last)];      // pad slots re-gather a valid row
            m[r] = (idx < r1) ? 1.f : 0.f;     // ...and are masked out here
            v[r] = fb[(size_t)cl * 16 + l16];
        }
#pragma unroll
        for (int r = 0; r < 4; r++) {
            uint4 u = v[r];
            float mr = m[r];
            acc[0] = fmaf(mr, fmaxf(fmaf(bf_lo(u.x), sc[0], sh[0]), 0.f), acc[0]);
            acc[1] = fmaf(mr, fmaxf(fmaf(bf_hi(u.x), sc[1], sh[1]), 0.f), acc[1]);
            acc[2] = fmaf(mr, fmaxf(fmaf(bf_lo(u.y), sc[2], sh[2]), 0.f), acc[2]);
            acc[3] = fmaf(mr, fmaxf(fmaf(bf_hi(u.y), sc[3], sh[3]), 0.f), acc[3]);
            acc[4] = fmaf(mr, fmaxf(fmaf(bf_lo(u.z), sc[4], sh[4]), 0.f), acc[4]);
            acc[5] = fmaf(mr, fmaxf(fmaf(bf_hi(u.z), sc[5], sh[5]), 0.f), acc[5]);
            acc[6] = fmaf(mr, fmaxf(fmaf(bf_lo(u.w), sc[6], sh[6]), 0.f), acc[6]);
            acc[7] = fmaf(mr, fmaxf(fmaf(bf_hi(u.w), sc[7], sh[7]), 0.f), acc[7]);
        }
    }
#pragma unroll
    for (int j = 0; j < 8; j++) {
        acc[j] += __shfl_down(acc[j], 32);
        acc[j] += __shfl_down(acc[j], 16);
    }
    if (lane < 16) {
        float inv = 1.0f / (float)(r1 - r0);
        uint4 o;
        o.x = pack_bf16(acc[0] * inv, acc[1] * inv);
        o.y = pack_bf16(acc[2] * inv, acc[3] * inv);
        o.z = pack_bf16(acc[4] * inv, acc[5] * inv);
        o.w = pack_bf16(acc[6] * inv, acc[7] * inv);
        out4[(size_t)node * 16 + l16] = o;
    }
}

// ---- MFMA conv (R0-proven LDS-tile version) --------------------------------
// FUSE1: write bf16 hb + per-block BN-stat partials (plain stores, NO atomics)
#define TSTRIDE 132
template<bool FUSE1>
__global__ __launch_bounds__(256) void conv_kernel(
    const uint* __restrict__ p1b, const uint* __restrict__ p2b,
    const uint* __restrict__ wb, const float* __restrict__ bias,
    float* __restrict__ outf, uint* __restrict__ outb,
    float* __restrict__ pstats, int n)
{
    extern __shared__ float smem[];   // FUSE1: tile[64][TSTRIDE]
    float* tile = smem;
    int w = threadIdx.x >> 6, lane = threadIdx.x & 63;
    int quad = lane >> 4, l15 = lane & 15;
    int nb = blockIdx.x * 64;

    const uint4* p1 = (const uint4*)p1b;
    const uint4* p2 = (const uint4*)p2b;
    const uint4* wv = (const uint4*)wb;

    uint4 B[8][2];
    int nt0 = w * 2;
#pragma unroll
    for (int ks = 0; ks < 8; ks++) {
#pragma unroll
        for (int t = 0; t < 2; t++)
            B[ks][t] = wv[(ks * 8 + nt0 + t) * 64 + lane];
    }

    float bv0 = bias[nt0 * 16 + l15];
    float bv1 = bias[nt0 * 16 + 16 + l15];

    for (int rt = 0; rt < 4; rt++) {
        int node = nb + rt * 16 + l15;
        int nc = min(node, n - 1);
        uint4 A[8];
#pragma unroll
        for (int ks = 0; ks < 4; ks++) A[ks] = p1[(size_t)nc * 16 + ks * 4 + quad];
#pragma unroll
        for (int ks = 0; ks < 4; ks++) A[ks + 4] = p2[(size_t)nc * 16 + ks * 4 + quad];

        f32x4 acc0 = {bv0, bv0, bv0, bv0};
        f32x4 acc1 = {bv1, bv1, bv1, bv1};
#pragma unroll
        for (int ks = 0; ks < 8; ks++) {
            s16x8 a = *(s16x8*)&A[ks];
            acc0 = __builtin_amdgcn_mfma_f32_16x16x32_bf16(a, *(s16x8*)&B[ks][0], acc0, 0, 0, 0);
            acc1 = __builtin_amdgcn_mfma_f32_16x16x32_bf16(a, *(s16x8*)&B[ks][1], acc1, 0, 0, 0);
        }
        // C/D: col = lane&15, row = quad*4 + reg
        int row0 = nb + rt * 16 + quad * 4;
        int colbase = nt0 * 16 + l15;
        if (FUSE1) {
            int rloc0 = rt * 16 + quad * 4;
#pragma unroll
            for (int reg = 0; reg < 4; reg++) {
                bool ok = (row0 + reg) < n;
                tile[(rloc0 + reg) * TSTRIDE + colbase]      = ok ? acc0[reg] : 0.f;
                tile[(rloc0 + reg) * TSTRIDE + colbase + 16] = ok ? acc1[reg] : 0.f;
            }
        } else {
#pragma unroll
            for (int reg = 0; reg < 4; reg++) {
                int row = row0 + reg;
                if (row < n) {
                    outf[(size_t)row * D + colbase] = acc0[reg];
                    outf[(size_t)row * D + colbase + 16] = acc1[reg];
                }
            }
        }
    }

    if (FUSE1) {
        __syncthreads();
        int colj = threadIdx.x & 127, half = threadIdx.x >> 7;
        float s = 0.f, ss = 0.f;
        for (int r = half * 32; r < half * 32 + 32; r++) {
            float v = tile[r * TSTRIDE + colj];
            s += v;
            ss += v * v;
        }
        float* pb = pstats + (size_t)blockIdx.x * 512 + half * 256;
        pb[colj] = s;
        pb[128 + colj] = ss;
        uint4* ob4 = (uint4*)outb;
#pragma unroll
        for (int q4 = 0; q4 < 4; q4++) {
            int idx = q4 * 256 + threadIdx.x;
            int r = idx >> 4, q = idx & 15;
            int row = nb + r;
            if (row < n) {
                float* tr = &tile[r * TSTRIDE + q * 8];
                uint4 o;
                o.x = pack_bf16(tr[0], tr[1]);
                o.y = pack_bf16(tr[2], tr[3]);
                o.z = pack_bf16(tr[4], tr[5]);
                o.w = pack_bf16(tr[6], tr[7]);
                ob4[(size_t)row * 16 + q] = o;
            }
        }
    }
}

// ---- fused reduce + BN finalize: 32 blocks, last-block-done computes scsh --
__global__ __launch_bounds__(256) void reduce_kernel(const float* __restrict__ pstats,
                                                     float* __restrict__ stats,
                                                     int* __restrict__ ctr,
                                                     const float* __restrict__ gamma,
                                                     const float* __restrict__ beta,
                                                     float* __restrict__ scsh,
                                                     int nparts, float n_inv)
{
    __shared__ int lastf;
    int j = threadIdx.x;
    int chunk = (nparts + gridDim.x - 1) / gridDim.x;
    int p0 = blockIdx.x * chunk;
    int p1 = min(p0 + chunk, nparts);
    float s = 0.f;
    for (int p = p0; p < p1; p++) s += pstats[(size_t)p * 256 + j];
    unsafeAtomicAdd(&stats[j], s);   // 32 adds/address total: negligible contention
    __threadfence();
    __syncthreads();
    if (threadIdx.x == 0) {
        int old = atomicAdd(ctr, 1);
        lastf = (old == (int)gridDim.x - 1) ? 1 : 0;
    }
    __syncthreads();
    if (lastf && j < 128) {
        float sm = atomicAdd(&stats[j], 0.0f);        // device-scope read
        float sq = atomicAdd(&stats[128 + j], 0.0f);
        float mean = sm * n_inv;
        float var = fmaxf(sq * n_inv - mean * mean, 0.f);
        float sc = gamma[j] * rsqrtf(var + EPS);
        scsh[j] = sc;
        scsh[128 + j] = beta[j] - mean * sc;
    }
}

extern "C" void kernel_launch(void* const* d_in, const int* in_sizes, int n_in,
                              void* d_out, int out_size, void* d_ws, size_t ws_size,
                              hipStream_t stream)
{
    const float* x     = (const float*)d_in[0];
    const int*   ei    = (const int*)d_in[1];
    const float* w1_l  = (const float*)d_in[2];
    const float* b1_l  = (const float*)d_in[3];
    const float* w1_r  = (const float*)d_in[4];
    const float* w2_l  = (const float*)d_in[5];
    const float* b2_l  = (const float*)d_in[6];
    const float* w2_r  = (const float*)d_in[7];
    const float* gamma = (const float*)d_in[8];
    const float* beta  = (const float*)d_in[9];

    int N = in_sizes[0] / D;
    int E = in_sizes[1] / 2;
    const int* src = ei;
    const int* dst = ei + E;

    int cblocks = (N + 63) / 64;
    int nbuck   = (N + 511) >> 9;               // 98
    int nblk    = (E + 4095) / 4096;            // 196
    int M       = nbuck * nblk;                 // 19208

    // workspace layout:
    // uints: aggb[N*64] | xb[(N+1)*64] | hb[N*64] | hbn[N*64] | wb1/wb2
    // uint2: ebuf[E]; floats: stats[256]|scanctr|redctr|scsh[256]|pstats
    // ints: rowptr|col|bcnt
    uint*  aggb   = (uint*)d_ws;
    uint*  xb     = aggb + (size_t)N * 64;
    uint*  hb     = xb + (size_t)(N + 1) * 64;
    uint*  hbn    = hb + (size_t)N * 64;
    uint*  wb1    = hbn + (size_t)N * 64;
    uint*  wb2    = wb1 + 16384;
    uint2* ebuf   = (uint2*)(wb2 + 16384);
    float* stats  = (float*)(ebuf + E);
    int*   scanctr= (int*)(stats + 256);
    int*   redctr = scanctr + 1;
    float* scsh   = stats + 258;
    float* pstats = scsh + 256;
    int*   rowptr = (int*)(pstats + (size_t)cblocks * 512);
    int*   col    = rowptr + N + 1;
    int*   bcnt   = col + E;

    // K1: prep || bcount (block 0 of prep range also zeroes stats+ctrs)
    int ncvt = N * 32;
    int total0 = ncvt + 8192 + 32;
    int pblocks = (total0 + 511) / 512;
    prep_count_kernel<<<nblk + pblocks, 512, 0, stream>>>(
        x, xb, ncvt, w1_l, w1_r, w2_l, w2_r, wb1, wb2,
        dst, bcnt, stats, E, nblk, nbuck);

    // K2-K4: finish CSR build
    bscan_kernel<<<1, 1024, 0, stream>>>(bcnt, M);
    bscatter_kernel<<<nblk, 512, 0, stream>>>(src, dst, bcnt, ebuf, E, nblk, nbuck);
    pbuild_kernel<<<nbuck, 512, 0, stream>>>(bcnt, ebuf, rowptr, col, N, nblk, nbuck, M, E);

    int ablocks = (N + 3) / 4;

    // K5/K6: layer 1
    agg_kernel<<<ablocks, 256, 0, stream>>>(rowptr, col, xb, aggb, N);
    conv_kernel<true><<<cblocks, 256, 64 * TSTRIDE * 4, stream>>>(
        aggb, xb, wb1, b1_l, nullptr, hb, pstats, N);

    // K7: BN reduce + finalize
    reduce_kernel<<<32, 256, 0, stream>>>(pstats, stats, redctr, gamma, beta, scsh,
                                          cblocks * 2, 1.0f / (float)N);

    // K8: agg layer 2 with fused BN/ReLU (also emits hbn root rows)
    aggbn_kernel<<<ablocks, 256, 0, stream>>>(rowptr, col, hb, aggb, hbn, scsh, N);

    // K9: conv layer 2 -> fp32 output
    conv_kernel<false><<<cblocks, 256, 1024, stream>>>(
        aggb, hbn, wb2, b2_l, (float*)d_out, nullptr, nullptr, N);
}

// Round 9
// 254.076 us; speedup vs baseline: 3.9000x; 1.0302x over previous
//
#include <hip/hip_runtime.h>

#define D 128
#define EPS 1e-5f
#define FB_EPB 8   // edges per thread in bcount/bscatter (512 thr -> 4096 edges/block)

typedef unsigned int uint;
typedef __attribute__((ext_vector_type(4))) float f32x4;
typedef __attribute__((ext_vector_type(8))) short s16x8;

// ---- bf16 pack/unpack helpers (RTNE) ---------------------------------------
__device__ __forceinline__ uint pack_bf16(float a, float b)
{
    uint ua = __float_as_uint(a);
    uint ub = __float_as_uint(b);
    ua += 0x7FFFu + ((ua >> 16) & 1u);
    ub += 0x7FFFu + ((ub >> 16) & 1u);
    return (ua >> 16) | (ub & 0xFFFF0000u);
}
__device__ __forceinline__ float bf_lo(uint v) { return __uint_as_float(v << 16); }
__device__ __forceinline__ float bf_hi(uint v) { return __uint_as_float(v & 0xFFFF0000u); }

// ---- K1: prep (xb, weight frags, zero row, zero stats) || bcount -----------
// Pure block-range fusion of two INDEPENDENT kernels. NO cross-block data
// handoff inside the kernel (R6 lesson: intra-kernel handoff needs device-
// scope loads at LLC latency; kernel boundaries flush for free).
__global__ __launch_bounds__(512) void prep_count_kernel(
    const float* __restrict__ x, uint* __restrict__ xb, int ncvt,
    const float* __restrict__ w1l, const float* __restrict__ w1r,
    const float* __restrict__ w2l, const float* __restrict__ w2r,
    uint* __restrict__ wb1, uint* __restrict__ wb2,
    const int* __restrict__ dst, int* __restrict__ bcnt,
    float* __restrict__ stats,
    int E, int nblk, int nbuck)
{
    __shared__ int cnt[128];
    int t = threadIdx.x;

    if (blockIdx.x < (uint)nblk) {
        // ---- bcount ----
        if (t < 128) cnt[t] = 0;
        __syncthreads();
        int e0 = blockIdx.x * (512 * FB_EPB);
#pragma unroll
        for (int k = 0; k < FB_EPB; k++) {
            int e = e0 + k * 512 + t;
            if (e < E) atomicAdd(&cnt[dst[e] >> 9], 1);
        }
        __syncthreads();
        if (t < nbuck) bcnt[t * nblk + blockIdx.x] = cnt[t];
    } else {
        // ---- prep ----
        if (blockIdx.x == (uint)nblk && t < 258) stats[t] = 0.f;  // stats+ctrs
        int idx = (blockIdx.x - nblk) * 512 + t;
        if (idx < ncvt) {
            float4 v = ((const float4*)x)[idx];
            uint2 o;
            o.x = pack_bf16(v.x, v.y);
            o.y = pack_bf16(v.z, v.w);
            ((uint2*)xb)[idx] = o;
        } else if (idx < ncvt + 8192) {
            int r = idx - ncvt;          // 0..8191
            int layer = r >> 12;
            int rem = r & 4095;
            int lane = rem & 63;
            int knt = rem >> 6;
            int kstep = knt >> 3, nt = knt & 7;
            int nn = nt * 16 + (lane & 15);
            int kbase = kstep * 32 + (lane >> 4) * 8;
            const float* wl = layer ? w2l : w1l;
            const float* wr = layer ? w2r : w1r;
            uint* wb = layer ? wb2 : wb1;
            float v[8];
#pragma unroll
            for (int j = 0; j < 8; j++) {
                int k = kbase + j;
                v[j] = (k < D) ? wl[nn * D + k] : wr[nn * D + (k - D)];
            }
            uint4 o;
            o.x = pack_bf16(v[0], v[1]);
            o.y = pack_bf16(v[2], v[3]);
            o.z = pack_bf16(v[4], v[5]);
            o.w = pack_bf16(v[6], v[7]);
            ((uint4*)wb)[(kstep * 8 + nt) * 64 + lane] = o;
        } else if (idx < ncvt + 8192 + 32) {
            // zero row (index N) for invalid-slot gathers in agg1
            ((uint2*)xb)[ncvt + (idx - ncvt - 8192)] = make_uint2(0, 0);
        }
    }
}

// ---- radix CSR phase 2: single-block exclusive scan of bcnt[M], append total
__global__ __launch_bounds__(1024) void bscan_kernel(int* __restrict__ bcnt, int M)
{
    __shared__ int sums[1024];
    int t = threadIdx.x;
    int chunk = (M + 1023) / 1024;
    int b0 = t * chunk;
    int b1 = min(b0 + chunk, M);
    int s = 0;
    for (int i = b0; i < b1; i++) s += bcnt[i];
    sums[t] = s;
    __syncthreads();
    for (int off = 1; off < 1024; off <<= 1) {
        int u = (t >= off) ? sums[t - off] : 0;
        __syncthreads();
        sums[t] += u;
        __syncthreads();
    }
    int run = sums[t] - s;
    for (int i = b0; i < b1; i++) { int v = bcnt[i]; bcnt[i] = run; run += v; }
    if (t == 1023) bcnt[M] = sums[1023];
}

// ---- radix CSR phase 3: scatter edges into bucket-contiguous ebuf ----------
__global__ __launch_bounds__(512) void bscatter_kernel(const int* __restrict__ src,
                                                       const int* __restrict__ dst,
                                                       const int* __restrict__ bcnt,
                                                       uint2* __restrict__ ebuf,
                                                       int E, int nblk, int nbuck)
{
    __shared__ int cnt[128], base[128];
    int t = threadIdx.x;
    if (t < 128) cnt[t] = 0;
    __syncthreads();
    int e0 = blockIdx.x * (512 * FB_EPB);
    int s[FB_EPB], d[FB_EPB], loc[FB_EPB];
#pragma unroll
    for (int k = 0; k < FB_EPB; k++) {
        int e = e0 + k * 512 + t;
        if (e < E) {
            s[k] = src[e];
            d[k] = dst[e];
            loc[k] = atomicAdd(&cnt[d[k] >> 9], 1);
        }
    }
    __syncthreads();
    if (t < nbuck) base[t] = bcnt[t * nblk + blockIdx.x];
    __syncthreads();
#pragma unroll
    for (int k = 0; k < FB_EPB; k++) {
        int e = e0 + k * 512 + t;
        if (e < E) {
            int b = d[k] >> 9;
            ebuf[base[b] + loc[k]] = make_uint2((uint)s[k], (uint)d[k]);
        }
    }
}

// ---- radix CSR phase 4: per-bucket build rowptr + col (LDS only) -----------
__global__ __launch_bounds__(512) void pbuild_kernel(const int* __restrict__ bcnt,
                                                     const uint2* __restrict__ ebuf,
                                                     int* __restrict__ rowptr,
                                                     int* __restrict__ col,
                                                     int n, int nblk, int nbuck, int M, int E)
{
    __shared__ int lcnt[512], lscan[512];
    int t = threadIdx.x;
    int b = blockIdx.x;
    int nb = b << 9;
    int e0 = bcnt[b * nblk];
    int e1 = (b + 1 < nbuck) ? bcnt[(b + 1) * nblk] : bcnt[M];
    lcnt[t] = 0;
    __syncthreads();
    for (int i = e0 + t; i < e1; i += 512)
        atomicAdd(&lcnt[(int)ebuf[i].y - nb], 1);
    __syncthreads();
    int s = lcnt[t];
    lscan[t] = s;
    __syncthreads();
    for (int off = 1; off < 512; off <<= 1) {
        int u = (t >= off) ? lscan[t - off] : 0;
        __syncthreads();
        lscan[t] += u;
        __syncthreads();
    }
    int start = e0 + lscan[t] - s;
    int ncnt = min(512, n - nb);
    if (t < ncnt) rowptr[nb + t] = start;
    if (b == nbuck - 1 && t == 0) rowptr[n] = E;
    lscan[t] = start;
    __syncthreads();
    for (int i = e0 + t; i < e1; i += 512) {
        uint2 ed = ebuf[i];
        int p = atomicAdd(&lscan[(int)ed.y - nb], 1);
        col[p] = (int)ed.x;
    }
}

// ---- gather aggregation: wave per node, 16-slot batches, zero-row padding --
// Plain unpack+add path (2 VALU ops/feature). Used for BOTH layers; layer 2
// gathers the post-BN hbn (bnapply materializes it once per node — R8's
// per-edge BN fusion doubled gather-path VALU, measured 62% VALUBusy).
__global__ __launch_bounds__(256) void agg_kernel(const int* __restrict__ rowptr,
                                                  const int* __restrict__ col,
                                                  const uint* __restrict__ featb,
                                                  uint* __restrict__ aggb, int n)
{
    int node = blockIdx.x * 4 + (threadIdx.x >> 6);
    if (node >= n) return;
    int lane = threadIdx.x & 63;
    int sub = lane >> 4, l16 = lane & 15;
    int r0 = rowptr[node], r1 = rowptr[node + 1];
    uint4* out4 = (uint4*)aggb;
    if (r0 == r1) {
        if (lane < 16) out4[(size_t)node * 16 + l16] = make_uint4(0, 0, 0, 0);
        return;
    }
    float acc[8] = {0.f, 0.f, 0.f, 0.f, 0.f, 0.f, 0.f, 0.f};
    const uint4* fb = (const uint4*)featb;
    int last = r1 - 1;

    for (int i = r0; i < r1; i += 16) {
        uint4 v[4];
#pragma unroll
        for (int r = 0; r < 4; r++) {
            int idx = i + r * 4 + sub;
            int cl = col[min(idx, last)];
            int c = (idx < r1) ? cl : n;       // n = zero row
            v[r] = fb[(size_t)c * 16 + l16];
        }
#pragma unroll
        for (int r = 0; r < 4; r++) {
            uint4 u = v[r];
            acc[0] += bf_lo(u.x); acc[1] += bf_hi(u.x);
            acc[2] += bf_lo(u.y); acc[3] += bf_hi(u.y);
            acc[4] += bf_lo(u.z); acc[5] += bf_hi(u.z);
            acc[6] += bf_lo(u.w); acc[7] += bf_hi(u.w);
        }
    }
#pragma unroll
    for (int j = 0; j < 8; j++) {
        acc[j] += __shfl_down(acc[j], 32);
        acc[j] += __shfl_down(acc[j], 16);
    }
    if (lane < 16) {
        float inv = 1.0f / (float)(r1 - r0);
        uint4 o;
        o.x = pack_bf16(acc[0] * inv, acc[1] * inv);
        o.y = pack_bf16(acc[2] * inv, acc[3] * inv);
        o.z = pack_bf16(acc[4] * inv, acc[5] * inv);
        o.w = pack_bf16(acc[6] * inv, acc[7] * inv);
        out4[(size_t)node * 16 + l16] = o;
    }
}

// ---- MFMA conv (R0-proven LDS-tile version) --------------------------------
// FUSE1: write bf16 hb + per-block BN-stat partials (plain stores, NO atomics)
#define TSTRIDE 132
template<bool FUSE1>
__global__ __launch_bounds__(256) void conv_kernel(
    const uint* __restrict__ p1b, const uint* __restrict__ p2b,
    const uint* __restrict__ wb, const float* __restrict__ bias,
    float* __restrict__ outf, uint* __restrict__ outb,
    float* __restrict__ pstats, int n)
{
    extern __shared__ float smem[];   // FUSE1: tile[64][TSTRIDE]
    float* tile = smem;
    int w = threadIdx.x >> 6, lane = threadIdx.x & 63;
    int quad = lane >> 4, l15 = lane & 15;
    int nb = blockIdx.x * 64;

    const uint4* p1 = (const uint4*)p1b;
    const uint4* p2 = (const uint4*)p2b;
    const uint4* wv = (const uint4*)wb;

    uint4 B[8][2];
    int nt0 = w * 2;
#pragma unroll
    for (int ks = 0; ks < 8; ks++) {
#pragma unroll
        for (int t = 0; t < 2; t++)
            B[ks][t] = wv[(ks * 8 + nt0 + t) * 64 + lane];
    }

    float bv0 = bias[nt0 * 16 + l15];
    float bv1 = bias[nt0 * 16 + 16 + l15];

    for (int rt = 0; rt < 4; rt++) {
        int node = nb + rt * 16 + l15;
        int nc = min(node, n - 1);
        uint4 A[8];
#pragma unroll
        for (int ks = 0; ks < 4; ks++) A[ks] = p1[(size_t)nc * 16 + ks * 4 + quad];
#pragma unroll
        for (int ks = 0; ks < 4; ks++) A[ks + 4] = p2[(size_t)nc * 16 + ks * 4 + quad];

        f32x4 acc0 = {bv0, bv0, bv0, bv0};
        f32x4 acc1 = {bv1, bv1, bv1, bv1};
#pragma unroll
        for (int ks = 0; ks < 8; ks++) {
            s16x8 a = *(s16x8*)&A[ks];
            acc0 = __builtin_amdgcn_mfma_f32_16x16x32_bf16(a, *(s16x8*)&B[ks][0], acc0, 0, 0, 0);
            acc1 = __builtin_amdgcn_mfma_f32_16x16x32_bf16(a, *(s16x8*)&B[ks][1], acc1, 0, 0, 0);
        }
        // C/D: col = lane&15, row = quad*4 + reg
        int row0 = nb + rt * 16 + quad * 4;
        int colbase = nt0 * 16 + l15;
        if (FUSE1) {
            int rloc0 = rt * 16 + quad * 4;
#pragma unroll
            for (int reg = 0; reg < 4; reg++) {
                bool ok = (row0 + reg) < n;
                tile[(rloc0 + reg) * TSTRIDE + colbase]      = ok ? acc0[reg] : 0.f;
                tile[(rloc0 + reg) * TSTRIDE + colbase + 16] = ok ? acc1[reg] : 0.f;
            }
        } else {
#pragma unroll
            for (int reg = 0; reg < 4; reg++) {
                int row = row0 + reg;
                if (row < n) {
                    outf[(size_t)row * D + colbase] = acc0[reg];
                    outf[(size_t)row * D + colbase + 16] = acc1[reg];
                }
            }
        }
    }

    if (FUSE1) {
        __syncthreads();
        int colj = threadIdx.x & 127, half = threadIdx.x >> 7;
        float s = 0.f, ss = 0.f;
        for (int r = half * 32; r < half * 32 + 32; r++) {
            float v = tile[r * TSTRIDE + colj];
            s += v;
            ss += v * v;
        }
        float* pb = pstats + (size_t)blockIdx.x * 512 + half * 256;
        pb[colj] = s;
        pb[128 + colj] = ss;
        uint4* ob4 = (uint4*)outb;
#pragma unroll
        for (int q4 = 0; q4 < 4; q4++) {
            int idx = q4 * 256 + threadIdx.x;
            int r = idx >> 4, q = idx & 15;
            int row = nb + r;
            if (row < n) {
                float* tr = &tile[r * TSTRIDE + q * 8];
                uint4 o;
                o.x = pack_bf16(tr[0], tr[1]);
                o.y = pack_bf16(tr[2], tr[3]);
                o.z = pack_bf16(tr[4], tr[5]);
                o.w = pack_bf16(tr[6], tr[7]);
                ob4[(size_t)row * 16 + q] = o;
            }
        }
    }
}

// ---- fused reduce + BN finalize: 32 blocks, last-block-done computes scsh --
__global__ __launch_bounds__(256) void reduce_kernel(const float* __restrict__ pstats,
                                                     float* __restrict__ stats,
                                                     int* __restrict__ ctr,
                                                     const float* __restrict__ gamma,
                                                     const float* __restrict__ beta,
                                                     float* __restrict__ scsh,
                                                     int nparts, float n_inv)
{
    __shared__ int lastf;
    int j = threadIdx.x;
    int chunk = (nparts + gridDim.x - 1) / gridDim.x;
    int p0 = blockIdx.x * chunk;
    int p1 = min(p0 + chunk, nparts);
    float s = 0.f;
    for (int p = p0; p < p1; p++) s += pstats[(size_t)p * 256 + j];
    unsafeAtomicAdd(&stats[j], s);   // 32 adds/address total: negligible contention
    __threadfence();
    __syncthreads();
    if (threadIdx.x == 0) {
        int old = atomicAdd(ctr, 1);
        lastf = (old == (int)gridDim.x - 1) ? 1 : 0;
    }
    __syncthreads();
    if (lastf && j < 128) {
        float sm = atomicAdd(&stats[j], 0.0f);        // device-scope read
        float sq = atomicAdd(&stats[128 + j], 0.0f);
        float mean = sm * n_inv;
        float var = fmaxf(sq * n_inv - mean * mean, 0.f);
        float sc = gamma[j] * rsqrtf(var + EPS);
        scsh[j] = sc;
        scsh[128 + j] = beta[j] - mean * sc;
    }
}

// ---- bnapply: hbn = relu(hb*sc+sh) (bf16 -> bf16), + zero row N ------------
__global__ __launch_bounds__(256) void bnapply_kernel(const uint* __restrict__ hb,
                                                      const float* __restrict__ scsh,
                                                      uint* __restrict__ hbn, int total2)
{
    __shared__ float scs[256];
    scs[threadIdx.x] = scsh[threadIdx.x];
    __syncthreads();
    int idx = blockIdx.x * 256 + threadIdx.x;
    if (blockIdx.x == 0 && threadIdx.x < 32)
        ((uint2*)hbn)[total2 + threadIdx.x] = make_uint2(0, 0);   // zero row
    if (idx >= total2) return;
    int j4 = (idx & 31) * 4;
    uint2 u = ((const uint2*)hb)[idx];
    float e0 = fmaxf(bf_lo(u.x) * scs[j4 + 0] + scs[128 + j4 + 0], 0.f);
    float e1 = fmaxf(bf_hi(u.x) * scs[j4 + 1] + scs[128 + j4 + 1], 0.f);
    float e2 = fmaxf(bf_lo(u.y) * scs[j4 + 2] + scs[128 + j4 + 2], 0.f);
    float e3 = fmaxf(bf_hi(u.y) * scs[j4 + 3] + scs[128 + j4 + 3], 0.f);
    uint2 o;
    o.x = pack_bf16(e0, e1);
    o.y = pack_bf16(e2, e3);
    ((uint2*)hbn)[idx] = o;
}

extern "C" void kernel_launch(void* const* d_in, const int* in_sizes, int n_in,
                              void* d_out, int out_size, void* d_ws, size_t ws_size,
                              hipStream_t stream)
{
    const float* x     = (const float*)d_in[0];
    const int*   ei    = (const int*)d_in[1];
    const float* w1_l  = (const float*)d_in[2];
    const float* b1_l  = (const float*)d_in[3];
    const float* w1_r  = (const float*)d_in[4];
    const float* w2_l  = (const float*)d_in[5];
    const float* b2_l  = (const float*)d_in[6];
    const float* w2_r  = (const float*)d_in[7];
    const float* gamma = (const float*)d_in[8];
    const float* beta  = (const float*)d_in[9];

    int N = in_sizes[0] / D;
    int E = in_sizes[1] / 2;
    const int* src = ei;
    const int* dst = ei + E;

    int cblocks = (N + 63) / 64;
    int nbuck   = (N + 511) >> 9;               // 98
    int nblk    = (E + 4095) / 4096;            // 196
    int M       = nbuck * nblk;                 // 19208

    // workspace layout:
    // uints: aggb[N*64] | xb[(N+1)*64] | hb[N*64] | hbn[(N+1)*64] | wb1/wb2
    // uint2: ebuf[E]; floats: stats[256]|scanctr|redctr|scsh[256]|pstats
    // ints: rowptr|col|bcnt
    uint*  aggb   = (uint*)d_ws;
    uint*  xb     = aggb + (size_t)N * 64;
    uint*  hb     = xb + (size_t)(N + 1) * 64;
    uint*  hbn    = hb + (size_t)N * 64;
    uint*  wb1    = hbn + (size_t)(N + 1) * 64;
    uint*  wb2    = wb1 + 16384;
    uint2* ebuf   = (uint2*)(wb2 + 16384);
    float* stats  = (float*)(ebuf + E);
    int*   scanctr= (int*)(stats + 256);
    int*   redctr = scanctr + 1;
    float* scsh   = stats + 258;
    float* pstats = scsh + 256;
    int*   rowptr = (int*)(pstats + (size_t)cblocks * 512);
    int*   col    = rowptr + N + 1;
    int*   bcnt   = col + E;

    // K1: prep || bcount (block nblk of prep range also zeroes stats+ctrs)
    int ncvt = N * 32;
    int total0 = ncvt + 8192 + 32;
    int pblocks = (total0 + 511) / 512;
    prep_count_kernel<<<nblk + pblocks, 512, 0, stream>>>(
        x, xb, ncvt, w1_l, w1_r, w2_l, w2_r, wb1, wb2,
        dst, bcnt, stats, E, nblk, nbuck);

    // K2-K4: finish CSR build
    bscan_kernel<<<1, 1024, 0, stream>>>(bcnt, M);
    bscatter_kernel<<<nblk, 512, 0, stream>>>(src, dst, bcnt, ebuf, E, nblk, nbuck);
    pbuild_kernel<<<nbuck, 512, 0, stream>>>(bcnt, ebuf, rowptr, col, N, nblk, nbuck, M, E);

    int ablocks = (N + 3) / 4;

    // K5/K6: layer 1
    agg_kernel<<<ablocks, 256, 0, stream>>>(rowptr, col, xb, aggb, N);
    conv_kernel<true><<<cblocks, 256, 64 * TSTRIDE * 4, stream>>>(
        aggb, xb, wb1, b1_l, nullptr, hb, pstats, N);

    // K7: BN reduce + finalize
    reduce_kernel<<<32, 256, 0, stream>>>(pstats, stats, redctr, gamma, beta, scsh,
                                          cblocks * 2, 1.0f / (float)N);

    // K8: BN apply (per-node, once) -> hbn (+ zero row)
    bnapply_kernel<<<(N * 32 + 255) / 256, 256, 0, stream>>>(hb, scsh, hbn, N * 32);

    // K9/K10: layer 2
    agg_kernel<<<ablocks, 256, 0, stream>>>(rowptr, col, hbn, aggb, N);
    conv_kernel<false><<<cblocks, 256, 1024, stream>>>(
        aggb, hbn, wb2, b2_l, (float*)d_out, nullptr, nullptr, N);
}